// Round 6
// baseline (6842.976 us; speedup 1.0000x reference)
//
#include <hip/hip_runtime.h>
#include <cstdint>
#include <cstddef>

// Problem constants: V=50000, E=300, NF=1, H=256, B=128, TH=32, TB=512, NC=4.
#define H_    256
#define NG    768      // 512 gate cols (r|u) + 256 candidate cols, packed
#define BATCH 128
#define TH_   32
#define TB_   512
#define E_    300
#define RPB   16             // batch rows per gru block
#define NBLK  (BATCH / RPB)  // 8 row-groups; fused grid = 16 blocks

typedef _Float16 half8 __attribute__((ext_vector_type(8)));
typedef float    floatx4 __attribute__((ext_vector_type(4)));

// Padded fragment-block addressing for h/rh LDS buffers.
// Block b (64 lanes' half8 units) lives at halfword offset b*8 + (b>>2)*8:
// +16B pad every 4 blocks. Keeps each lane's 8 halves contiguous & 16B-aligned
// (ds_read_b128 legal) while spreading scalar epilogue accesses over all 32
// banks (writer banks: 4r+20*quad+16*(l15>>3)+((l15&7)>>1) covers 0..31 2-way).
__device__ __forceinline__ int fragoff(int b) { return b * 8 + (b >> 2) * 8; }
__device__ __forceinline__ int fragpos(int m, int k) {
  int b = (k >> 5) * 64 + (((k & 31) >> 3) * 16) + m;
  return fragoff(b) + (k & 7);
}
#define FRAGSZ 5120   // fragoff(511)+8 = 5112, rounded

// ---------------------------------------------------------------------------
// Pack input-projection weights (fp32) + bias. j<512 -> Wg col j; else Wc.
// ---------------------------------------------------------------------------
__global__ __launch_bounds__(256) void pack_k(
    const float* __restrict__ Wg, const float* __restrict__ bg,
    const float* __restrict__ Wc, const float* __restrict__ bc, int din,
    float* __restrict__ Bx, float* __restrict__ bias)
{
  int idx = blockIdx.x * 256 + threadIdx.x;
  if (idx < NG) bias[idx] = (idx < 2 * H_) ? bg[idx] : bc[idx - 2 * H_];
  int tot = din * NG;
  if (idx >= tot) return;
  int k = idx / NG, j = idx % NG;
  float v = (j < 2 * H_) ? Wg[k * 2 * H_ + j] : Wc[k * H_ + (j - 2 * H_)];
  Bx[(size_t)k * NG + j] = v;
}

// ---------------------------------------------------------------------------
// Pack recurrent weights into fp16 MFMA B-fragment order (R3-validated).
// ---------------------------------------------------------------------------
__global__ __launch_bounds__(256) void pack_w(
    const float* __restrict__ Wg, const float* __restrict__ Wc, int din,
    _Float16* __restrict__ wpk)
{
  int idx = blockIdx.x * 256 + threadIdx.x;
  if (idx >= 384 * 64) return;
  int tile = idx >> 6, lane = idx & 63;
  const float* W; int ncols, nt, kt;
  if (tile < 256) { nt = tile >> 3; kt = tile & 7; W = Wg; ncols = 2 * H_; }
  else { int tt = tile - 256; nt = tt >> 3; kt = tt & 7; W = Wc; ncols = H_; }
  int n = nt * 16 + (lane & 15);
  int kb = kt * 32 + (lane >> 4) * 8;
  _Float16* dst = wpk + ((size_t)(tile * 64 + lane)) * 8;
#pragma unroll
  for (int j = 0; j < 8; ++j)
    dst[j] = (_Float16)W[(size_t)(din + kb + j) * ncols + n];
}

// ---------------------------------------------------------------------------
// seqlen[b] = #nonzero ids in row b (valid steps form a prefix).
// ---------------------------------------------------------------------------
__global__ __launch_bounds__(256) void seq_k(const int* __restrict__ ids, int T,
                                             int* __restrict__ seq)
{
  __shared__ int red[256];
  int b = blockIdx.x, tid = threadIdx.x;
  int cnt = 0;
  for (int t = tid; t < T; t += 256) cnt += (ids[b * T + t] != 0) ? 1 : 0;
  red[tid] = cnt;
  __syncthreads();
  for (int s = 128; s > 0; s >>= 1) {
    if (tid < s) red[tid] += red[tid + s];
    __syncthreads();
  }
  if (tid == 0) seq[b] = red[0];
}

// ---------------------------------------------------------------------------
// Input-projection GEMM over a time-chunk (fp32):
//   G[(tl*BATCH + b)*NG + col] = A[row, :K] @ Bp[K, 768] + bias,
//   row = b*tc + tl (time-major G output for the persistent gru).
// ---------------------------------------------------------------------------
__global__ __launch_bounds__(256) void gemm_in(
    const float* __restrict__ Adir, const int* __restrict__ ids,
    const float* __restrict__ emb,
    const float* __restrict__ Bp, const float* __restrict__ bias,
    float* __restrict__ G, int nrows, int K, int t0, int tc, int T)
{
  __shared__ float As[16][68];
  __shared__ float Bs[16][64];
  const int tid = threadIdx.x;
  const int m0 = blockIdx.x * 64;
  const int n0 = blockIdx.y * 64;
  const int tm = (tid >> 4) * 4;
  const int tn = (tid & 15) * 4;
  const int la_r = tid >> 4;
  const int la_k = tid & 15;
  const int lb_n = tid & 63;
  const int lb_k = tid >> 6;
  float acc[4][4] = {{0.f}};

  for (int k0 = 0; k0 < K; k0 += 16) {
#pragma unroll
    for (int p = 0; p < 4; ++p) {
      int r = p * 16 + la_r;
      int row = m0 + r;
      int kg = k0 + la_k;
      float v = 0.f;
      if (row < nrows && kg < K) {
        if (Adir) v = Adir[(size_t)row * K + kg];
        else {
          int b = row / tc, tl = row % tc;
          v = emb[(size_t)ids[b * T + t0 + tl] * K + kg];
        }
      }
      As[la_k][r] = v;
    }
#pragma unroll
    for (int p = 0; p < 4; ++p) {
      int kl = p * 4 + lb_k;
      int kg = k0 + kl;
      Bs[kl][lb_n] = (kg < K) ? Bp[(size_t)kg * NG + n0 + lb_n] : 0.f;
    }
    __syncthreads();
#pragma unroll
    for (int kk = 0; kk < 16; ++kk) {
      float a0 = As[kk][tm + 0], a1 = As[kk][tm + 1];
      float a2 = As[kk][tm + 2], a3 = As[kk][tm + 3];
      float b0 = Bs[kk][tn + 0], b1 = Bs[kk][tn + 1];
      float b2 = Bs[kk][tn + 2], b3 = Bs[kk][tn + 3];
      acc[0][0] += a0 * b0; acc[0][1] += a0 * b1; acc[0][2] += a0 * b2; acc[0][3] += a0 * b3;
      acc[1][0] += a1 * b0; acc[1][1] += a1 * b1; acc[1][2] += a1 * b2; acc[1][3] += a1 * b3;
      acc[2][0] += a2 * b0; acc[2][1] += a2 * b1; acc[2][2] += a2 * b2; acc[2][3] += a2 * b3;
      acc[3][0] += a3 * b0; acc[3][1] += a3 * b1; acc[3][2] += a3 * b2; acc[3][3] += a3 * b3;
    }
    __syncthreads();
  }
#pragma unroll
  for (int i = 0; i < 4; ++i) {
    int row = m0 + tm + i;
    if (row < nrows) {
      int b = row / tc, tl = row - b * tc;
      float* gout = G + ((size_t)tl * BATCH + b) * NG + n0 + tn;
#pragma unroll
      for (int j = 0; j < 4; ++j)
        gout[j] = acc[i][j] + bias[n0 + tn + j];
    }
  }
}

// ---------------------------------------------------------------------------
// Persistent-weight fused GRU. Grid = 16 blocks x 512 thr, 1 block/CU
// (LDS ~153 KB). amdgpu_waves_per_eu(2,2) -> 256-VGPR budget so the 192
// weight VGPRs stay resident (launch_bounds(512,1) failed to raise the cap:
// R4/R5 both allocated 128). h/rh LDS buffers use padded fragment blocks
// (fragoff) and Gs rows are padded to 772 floats -> all scalar epilogue
// LDS accesses conflict-free.
// ---------------------------------------------------------------------------
__global__ __attribute__((amdgpu_flat_work_group_size(512, 512),
                          amdgpu_waves_per_eu(2, 2))) void gru_pers(
    const float* __restrict__ G0, const _Float16* __restrict__ W0,
    const int* __restrict__ seq, float* __restrict__ out0,
    float* __restrict__ st0, int t00, int tc,
    const float* __restrict__ G1, const _Float16* __restrict__ W1,
    float* __restrict__ st1, int t01)
{
  __shared__ __align__(16) _Float16 hpk[2][FRAGSZ];   // h hi/lo, padded frag
  __shared__ __align__(16) _Float16 rpk[2][FRAGSZ];   // r*h hi/lo, padded frag
  __shared__ float uf[16][260];                       // u gate (+4 pad)
  __shared__ __align__(16) float Gs[2][16][772];      // staged G, padded rows
  __shared__ int seqL[16];

  const int bid = blockIdx.x;
  const float* G; const _Float16* Wsrc; float* outp; float* state; int t0, rg;
  if (bid < NBLK) { G = G0; Wsrc = W0; outp = out0; state = st0; t0 = t00; rg = bid; }
  else            { G = G1; Wsrc = W1; outp = nullptr; state = st1; t0 = t01; rg = bid - NBLK; }
  if (!G) return;

  const int tid = threadIdx.x;
  const int w = tid >> 6, lane = tid & 63;
  const int quad = lane >> 4, l15 = lane & 15;

  // --- resident weights: 48 x half8 = 192 VGPRs per wave -------------------
  half8 wg[4][8], wc2[2][8];
#pragma unroll
  for (int s = 0; s < 4; ++s)
#pragma unroll
    for (int kt = 0; kt < 8; ++kt)
      wg[s][kt] = *(const half8*)&Wsrc[(size_t)(((w * 4 + s) * 8 + kt) * 64 + lane) * 8];
#pragma unroll
  for (int s = 0; s < 2; ++s)
#pragma unroll
    for (int kt = 0; kt < 8; ++kt)
      wc2[s][kt] = *(const half8*)&Wsrc[(size_t)((256 + (w * 2 + s) * 8 + kt) * 64 + lane) * 8];

  if (tid < 16) seqL[tid] = seq[rg * RPB + tid];
  for (int idx = tid; idx < 4096; idx += 512) {
    int m = idx & 15, k = idx >> 4;
    float v = (t0 == 0) ? 0.f : state[(size_t)(rg * RPB + m) * H_ + k];
    _Float16 hi = (_Float16)v;
    int pos = fragpos(m, k);
    hpk[0][pos] = hi;
    hpk[1][pos] = (_Float16)(v - (float)hi);
  }
  __syncthreads();
  int Smax = 0;
#pragma unroll
  for (int i = 0; i < 16; ++i) Smax = max(Smax, seqL[i]);
  int steps = Smax - t0;
  if (steps < 0) steps = 0;
  if (steps > tc) steps = tc;

  // async staging: wave w copies segments w*6..w*6+5 (1 KB each, 16 B/lane).
  // dst honors the 772-float row pad; each instruction's 256-float span is
  // contiguous (global_load_lds: wave-uniform base + lane*16).
  const float* gblk = G + (size_t)rg * RPB * NG;    // + t*BATCH*NG per step
  auto stage = [&](int t, int buf) {
    const float* gp = gblk + (size_t)t * BATCH * NG;
#pragma unroll
    for (int i = 0; i < 6; ++i) {
      int seg = w * 6 + i;                           // 0..47
      int rr = seg / 3, part = seg - rr * 3;
      const float* gsrc = gp + (size_t)seg * 256 + lane * 4;
      __builtin_amdgcn_global_load_lds(
          (const __attribute__((address_space(1))) unsigned int*)gsrc,
          (__attribute__((address_space(3))) unsigned int*)&Gs[buf][rr][part * 256],
          16, 0, 0);
    }
  };
  if (steps > 0) stage(0, 0);
  __syncthreads();

  for (int t = 0; t < steps; ++t) {
    const int tg = t0 + t, buf = t & 1;
    if (t + 1 < steps) stage(t + 1, buf ^ 1);   // async prefetch next step's G
    // ---------------- phase A: 512 gate cols ----------------
    floatx4 acc[4] = {};
#pragma unroll
    for (int kt = 0; kt < 8; ++kt) {
      int ho = fragoff(kt * 64 + lane);
      half8 ahi = *(const half8*)&hpk[0][ho];
      half8 alo = *(const half8*)&hpk[1][ho];
#pragma unroll
      for (int s = 0; s < 4; ++s) {
        acc[s] = __builtin_amdgcn_mfma_f32_16x16x32_f16(ahi, wg[s][kt], acc[s], 0, 0, 0);
        acc[s] = __builtin_amdgcn_mfma_f32_16x16x32_f16(alo, wg[s][kt], acc[s], 0, 0, 0);
      }
    }
    if (w < 4) {           // r gates: cols 0..255
#pragma unroll
      for (int s = 0; s < 4; ++s) {
        int k = w * 64 + s * 16 + l15;
#pragma unroll
        for (int r = 0; r < 4; ++r) {
          int row = quad * 4 + r;
          float pre = acc[s][r] + Gs[buf][row][k];
          float gate = 1.f / (1.f + __expf(-pre));
          int pos = fragpos(row, k);
          float hold = (float)hpk[0][pos] + (float)hpk[1][pos];
          float rh = gate * hold;
          _Float16 hi = (_Float16)rh;
          rpk[0][pos] = hi;
          rpk[1][pos] = (_Float16)(rh - (float)hi);
        }
      }
    } else {               // u gates: cols 256..511
#pragma unroll
      for (int s = 0; s < 4; ++s) {
        int k = (w - 4) * 64 + s * 16 + l15;
#pragma unroll
        for (int r = 0; r < 4; ++r) {
          int row = quad * 4 + r;
          float pre = acc[s][r] + Gs[buf][row][256 + k];
          uf[row][k] = 1.f / (1.f + __expf(-pre));
        }
      }
    }
    __syncthreads();
    // ---------------- phase B: 256 candidate cols ----------------
    floatx4 accB[2] = {};
#pragma unroll
    for (int kt = 0; kt < 8; ++kt) {
      int ho = fragoff(kt * 64 + lane);
      half8 ahi = *(const half8*)&rpk[0][ho];
      half8 alo = *(const half8*)&rpk[1][ho];
#pragma unroll
      for (int s = 0; s < 2; ++s) {
        accB[s] = __builtin_amdgcn_mfma_f32_16x16x32_f16(ahi, wc2[s][kt], accB[s], 0, 0, 0);
        accB[s] = __builtin_amdgcn_mfma_f32_16x16x32_f16(alo, wc2[s][kt], accB[s], 0, 0, 0);
      }
    }
#pragma unroll
    for (int s = 0; s < 2; ++s) {
      int k = w * 32 + s * 16 + l15;
#pragma unroll
      for (int r = 0; r < 4; ++r) {
        int row = quad * 4 + r;
        float pre = accB[s][r] + Gs[buf][row][512 + k];
        float e2 = __expf(2.f * pre);
        float c = 1.f - 2.f / (1.f + e2);      // tanh
        int pos = fragpos(row, k);
        float hold = (float)hpk[0][pos] + (float)hpk[1][pos];
        float u = uf[row][k];
        float hn = u * hold + (1.f - u) * c;
        bool valid = tg < seqL[row];
        if (!valid) hn = hold;
        _Float16 hi = (_Float16)hn;
        hpk[0][pos] = hi;
        hpk[1][pos] = (_Float16)(hn - (float)hi);
        if (outp)
          outp[((size_t)(rg * RPB + row) * tc + t) * H_ + k] = valid ? hn : 0.f;
      }
    }
    __syncthreads();
  }
  for (int idx = tid; idx < 4096; idx += 512) {
    int m = idx & 15, k = idx >> 4;
    int pos = fragpos(m, k);
    state[(size_t)(rg * RPB + m) * H_ + k] = (float)hpk[0][pos] + (float)hpk[1][pos];
  }
}

// ---------------------------------------------------------------------------
// Final prediction: out[b, c] = [h_head | h_body] @ W_pred + b_pred.
// ---------------------------------------------------------------------------
__global__ __launch_bounds__(512) void pred_k(
    const float* __restrict__ hh, const float* __restrict__ hb,
    const float* __restrict__ Wp, const float* __restrict__ bpred,
    float* __restrict__ out)
{
  int tid = threadIdx.x;
  int b = tid >> 2, c = tid & 3;
  float acc = bpred[c];
  for (int k = 0; k < H_; ++k) acc += hh[b * H_ + k] * Wp[k * 4 + c];
  for (int k = 0; k < H_; ++k) acc += hb[b * H_ + k] * Wp[(H_ + k) * 4 + c];
  out[b * 4 + c] = acc;
}

// ---------------------------------------------------------------------------
extern "C" void kernel_launch(void* const* d_in, const int* in_sizes, int n_in,
                              void* d_out, int out_size, void* d_ws, size_t ws_size,
                              hipStream_t stream)
{
  (void)in_sizes; (void)n_in; (void)out_size;
  const int*   idsH = (const int*)  d_in[0];
  const int*   idsB = (const int*)  d_in[1];
  const float* emb  = (const float*)d_in[2];
  const float* Wp   = (const float*)d_in[3];
  const float* bp   = (const float*)d_in[4];
  const float* W[4][4];   // [hd0,hd1,bd0,bd1][Wg,bg,Wc,bc]
  for (int s = 0; s < 4; ++s)
    for (int q = 0; q < 4; ++q)
      W[s][q] = (const float*)d_in[5 + s * 4 + q];

  // choose time-chunk CH to fit ws_size (two G buffers for the pipeline)
  const size_t fixed_f = 1600000;
  int CH = 64;
  while (CH > 8 && (fixed_f + (size_t)BATCH * CH * (2 * NG + H_)) * 4 > ws_size)
    CH >>= 1;
  const int CHH = (CH < TH_) ? CH : TH_;

  float* wbase = (float*)d_ws;
  size_t off = 0;
  auto alloc = [&](size_t n) {
    float* p = wbase + off; off += (n + 255) & ~(size_t)255; return p;
  };
  int* seqH = (int*)alloc(BATCH);
  int* seqB = (int*)alloc(BATCH);
  float* Bx[4]; float* bi[4]; _Float16* Wpk[4];
  const int din[4] = {E_, H_, E_, H_};
  for (int s = 0; s < 4; ++s) {
    Bx[s]  = alloc((size_t)din[s] * NG);
    bi[s]  = alloc(NG);
    Wpk[s] = (_Float16*)alloc(384 * 64 * 8 / 2);   // 384 KB fp16
  }
  float* st0 = alloc((size_t)BATCH * H_);   // layer-0 carry (per stream, reused)
  float* hfH = alloc((size_t)BATCH * H_);   // head layer-1 carry/final
  float* hfB = alloc((size_t)BATCH * H_);   // body layer-1 carry/final
  float* Gc0 = alloc((size_t)BATCH * CH * NG);
  float* Gc1 = alloc((size_t)BATCH * CH * NG);
  float* Oc  = alloc((size_t)BATCH * CH * H_);
  (void)ws_size;

  // 1. pack weights
  for (int s = 0; s < 4; ++s) {
    int tot = din[s] * NG;
    pack_k<<<(tot + 255) / 256, 256, 0, stream>>>(
        W[s][0], W[s][1], W[s][2], W[s][3], din[s], Bx[s], bi[s]);
    pack_w<<<(384 * 64 + 255) / 256, 256, 0, stream>>>(
        W[s][0], W[s][2], din[s], Wpk[s]);
  }
  // 2. seqlens
  seq_k<<<BATCH, 256, 0, stream>>>(idsH, TH_, seqH);
  seq_k<<<BATCH, 256, 0, stream>>>(idsB, TB_, seqB);

  // 3. chunk-pipelined stream: fused dispatch runs L0(c) and L1(c-1)
  auto run_stream = [&](const int* ids, int T, int chs, const int* seq,
                        int l0, int l1, float* hf) {
    int nchunks = T / chs;
    int rows = BATCH * chs;
    dim3 g(rows / 64, NG / 64);
    for (int c = 0; c < nchunks; ++c) {
      int t0 = c * chs;
      gemm_in<<<g, 256, 0, stream>>>(nullptr, ids, emb, Bx[l0], bi[l0], Gc0,
                                     rows, E_, t0, chs, T);
      gru_pers<<<2 * NBLK, 512, 0, stream>>>(
          Gc0, Wpk[l0], seq, Oc, st0, t0, chs,
          (c > 0) ? Gc1 : nullptr, Wpk[l1], hf, (c - 1) * chs);
      gemm_in<<<g, 256, 0, stream>>>(Oc, nullptr, nullptr, Bx[l1], bi[l1], Gc1,
                                     rows, H_, 0, chs, T);
    }
    // drain: last layer-1 chunk
    gru_pers<<<2 * NBLK, 512, 0, stream>>>(
        nullptr, Wpk[l0], seq, nullptr, st0, 0, chs,
        Gc1, Wpk[l1], hf, (nchunks - 1) * chs);
  };
  run_stream(idsH, TH_, CHH, seqH, 0, 1, hfH);   // headline (hd0, hd1)
  run_stream(idsB, TB_, CH,  seqB, 2, 3, hfB);   // body     (bd0, bd1)

  // 4. prediction head
  pred_k<<<1, 512, 0, stream>>>(hfH, hfB, Wp, bp, (float*)d_out);
}

// Round 7
// 6534.940 us; speedup vs baseline: 1.0471x; 1.0471x over previous
//
#include <hip/hip_runtime.h>
#include <cstdint>
#include <cstddef>

// Problem constants: V=50000, E=300, NF=1, H=256, B=128, TH=32, TB=512, NC=4.
#define H_    256
#define NG    768      // 512 gate cols (r|u) + 256 candidate cols, packed
#define BATCH 128
#define TH_   32
#define TB_   512
#define E_    300
#define RPB   16             // batch rows per gru block
#define NBLK  (BATCH / RPB)  // 8 row-groups; fused grid = 16 blocks

typedef _Float16 half8 __attribute__((ext_vector_type(8)));
typedef float    floatx4 __attribute__((ext_vector_type(4)));

// ---------------------------------------------------------------------------
// Pack input-projection weights (fp32) + bias. j<512 -> Wg col j; else Wc.
// ---------------------------------------------------------------------------
__global__ __launch_bounds__(256) void pack_k(
    const float* __restrict__ Wg, const float* __restrict__ bg,
    const float* __restrict__ Wc, const float* __restrict__ bc, int din,
    float* __restrict__ Bx, float* __restrict__ bias)
{
  int idx = blockIdx.x * 256 + threadIdx.x;
  if (idx < NG) bias[idx] = (idx < 2 * H_) ? bg[idx] : bc[idx - 2 * H_];
  int tot = din * NG;
  if (idx >= tot) return;
  int k = idx / NG, j = idx % NG;
  float v = (j < 2 * H_) ? Wg[k * 2 * H_ + j] : Wc[k * H_ + (j - 2 * H_)];
  Bx[(size_t)k * NG + j] = v;
}

// ---------------------------------------------------------------------------
// Pack recurrent weights into fp16 MFMA B-fragment order, retiled for the
// per-wave column assignment of gru_pers:
//   tiles [0,16):  r-gates,  tile = w*2+s -> Wg col n0 = w*32+s*16
//   tiles [16,32): u-gates,  Wg col n0 = 256 + w*32+s*16
//   tiles [32,48): candidate, Wc col n0 = w*32+s*16
// B-frag content (R3-validated): lane l, elem j ->
//   W[din + kt*32 + (l>>4)*8 + j][n0 + (l&15)]
// ---------------------------------------------------------------------------
__global__ __launch_bounds__(256) void pack_w(
    const float* __restrict__ Wg, const float* __restrict__ Wc, int din,
    _Float16* __restrict__ wpk)
{
  int idx = blockIdx.x * 256 + threadIdx.x;
  if (idx >= 48 * 64) return;
  int tile = idx >> 6, lane = idx & 63;
  int grp = tile >> 4, tt = tile & 15;
  int wv = tt >> 1, s = tt & 1;
  const float* W; int ncols, n0;
  if (grp == 0)      { W = Wg; ncols = 2 * H_; n0 = wv * 32 + s * 16; }
  else if (grp == 1) { W = Wg; ncols = 2 * H_; n0 = 256 + wv * 32 + s * 16; }
  else               { W = Wc; ncols = H_;     n0 = wv * 32 + s * 16; }
  int n = n0 + (lane & 15);
  int kb = (lane >> 4) * 8;
#pragma unroll
  for (int kt = 0; kt < 8; ++kt) {
    _Float16* dst = wpk + ((size_t)(tile * 8 + kt) * 64 + lane) * 8;
#pragma unroll
    for (int j = 0; j < 8; ++j)
      dst[j] = (_Float16)W[(size_t)(din + kt * 32 + kb + j) * ncols + n];
  }
}

// ---------------------------------------------------------------------------
// seqlen[b] = #nonzero ids in row b (valid steps form a prefix).
// ---------------------------------------------------------------------------
__global__ __launch_bounds__(256) void seq_k(const int* __restrict__ ids, int T,
                                             int* __restrict__ seq)
{
  __shared__ int red[256];
  int b = blockIdx.x, tid = threadIdx.x;
  int cnt = 0;
  for (int t = tid; t < T; t += 256) cnt += (ids[b * T + t] != 0) ? 1 : 0;
  red[tid] = cnt;
  __syncthreads();
  for (int s = 128; s > 0; s >>= 1) {
    if (tid < s) red[tid] += red[tid + s];
    __syncthreads();
  }
  if (tid == 0) seq[b] = red[0];
}

// ---------------------------------------------------------------------------
// Input-projection GEMM over a time-chunk (fp32):
//   G[(tl*BATCH + b)*NG + col] = A[row, :K] @ Bp[K, 768] + bias,
//   row = b*tc + tl (time-major G output for the persistent gru).
// ---------------------------------------------------------------------------
__global__ __launch_bounds__(256) void gemm_in(
    const float* __restrict__ Adir, const int* __restrict__ ids,
    const float* __restrict__ emb,
    const float* __restrict__ Bp, const float* __restrict__ bias,
    float* __restrict__ G, int nrows, int K, int t0, int tc, int T)
{
  __shared__ float As[16][68];
  __shared__ float Bs[16][64];
  const int tid = threadIdx.x;
  const int m0 = blockIdx.x * 64;
  const int n0 = blockIdx.y * 64;
  const int tm = (tid >> 4) * 4;
  const int tn = (tid & 15) * 4;
  const int la_r = tid >> 4;
  const int la_k = tid & 15;
  const int lb_n = tid & 63;
  const int lb_k = tid >> 6;
  float acc[4][4] = {{0.f}};

  for (int k0 = 0; k0 < K; k0 += 16) {
#pragma unroll
    for (int p = 0; p < 4; ++p) {
      int r = p * 16 + la_r;
      int row = m0 + r;
      int kg = k0 + la_k;
      float v = 0.f;
      if (row < nrows && kg < K) {
        if (Adir) v = Adir[(size_t)row * K + kg];
        else {
          int b = row / tc, tl = row % tc;
          v = emb[(size_t)ids[b * T + t0 + tl] * K + kg];
        }
      }
      As[la_k][r] = v;
    }
#pragma unroll
    for (int p = 0; p < 4; ++p) {
      int kl = p * 4 + lb_k;
      int kg = k0 + kl;
      Bs[kl][lb_n] = (kg < K) ? Bp[(size_t)kg * NG + n0 + lb_n] : 0.f;
    }
    __syncthreads();
#pragma unroll
    for (int kk = 0; kk < 16; ++kk) {
      float a0 = As[kk][tm + 0], a1 = As[kk][tm + 1];
      float a2 = As[kk][tm + 2], a3 = As[kk][tm + 3];
      float b0 = Bs[kk][tn + 0], b1 = Bs[kk][tn + 1];
      float b2 = Bs[kk][tn + 2], b3 = Bs[kk][tn + 3];
      acc[0][0] += a0 * b0; acc[0][1] += a0 * b1; acc[0][2] += a0 * b2; acc[0][3] += a0 * b3;
      acc[1][0] += a1 * b0; acc[1][1] += a1 * b1; acc[1][2] += a1 * b2; acc[1][3] += a1 * b3;
      acc[2][0] += a2 * b0; acc[2][1] += a2 * b1; acc[2][2] += a2 * b2; acc[2][3] += a2 * b3;
      acc[3][0] += a3 * b0; acc[3][1] += a3 * b1; acc[3][2] += a3 * b2; acc[3][3] += a3 * b3;
    }
    __syncthreads();
  }
#pragma unroll
  for (int i = 0; i < 4; ++i) {
    int row = m0 + tm + i;
    if (row < nrows) {
      int b = row / tc, tl = row - b * tc;
      float* gout = G + ((size_t)tl * BATCH + b) * NG + n0 + tn;
#pragma unroll
      for (int j = 0; j < 4; ++j)
        gout[j] = acc[i][j] + bias[n0 + tn + j];
    }
  }
}

// ---------------------------------------------------------------------------
// Persistent-weight fused GRU. Grid = 16 blocks x 512 thr, 1 block/CU.
// Wave w owns hidden dims [w*32, w*32+32) in BOTH phases; per-thread fp32
// h_reg/u_reg masters eliminate uf[] and scalar hold reads. Weights (48
// B-frags = 192 regs/wave) are pinned into AGPRs via inline asm each step
// so the scheduler cannot sink the loads back into L2 streaming (R4-R6:
// VGPR cap 128 -> compiler re-streamed 384 KB/step; attributes didn't help).
// h/rh LDS frag layout: block(m,k) = (k>>5)*64 + s*32 + r*8 + quad_m*2 +
// (l15>>3) -> scalar b16 writes are 2-way (free) across all 32 banks, b128
// A-frag reads perfectly balanced (both verified against bank equations).
// Single-fp16 h in MFMA (hi/lo dropped): halves MFMA + frag traffic.
// ---------------------------------------------------------------------------
__global__ __launch_bounds__(512, 1) void gru_pers(
    const float* __restrict__ G0, const _Float16* __restrict__ W0,
    const int* __restrict__ seq, float* __restrict__ out0,
    float* __restrict__ st0, int t00, int tc,
    const float* __restrict__ G1, const _Float16* __restrict__ W1,
    float* __restrict__ st1, int t01)
{
  __shared__ __align__(16) _Float16 hpk[4096];    // h frags (fp16)
  __shared__ __align__(16) _Float16 rpk[4096];    // r*h frags (fp16)
  __shared__ __align__(16) float Gs[2][16][772];  // staged G, padded rows

  const int bid = blockIdx.x;
  const float* G; const _Float16* Wsrc; float* outp; float* state; int t0, rg;
  if (bid < NBLK) { G = G0; Wsrc = W0; outp = out0; state = st0; t0 = t00; rg = bid; }
  else            { G = G1; Wsrc = W1; outp = nullptr; state = st1; t0 = t01; rg = bid - NBLK; }
  if (!G) return;

  const int tid = threadIdx.x;
  const int w = tid >> 6, lane = tid & 63;
  const int quad = lane >> 4, l15 = lane & 15;

  // --- load weights once; pin into AGPRs ----------------------------------
  floatx4 wt[6][8];
#pragma unroll
  for (int i = 0; i < 6; ++i) {
    const int tile = (i >> 1) * 16 + w * 2 + (i & 1);
#pragma unroll
    for (int kt = 0; kt < 8; ++kt) {
      wt[i][kt] = *(const floatx4*)&Wsrc[((size_t)(tile * 8 + kt) * 64 + lane) * 8];
      asm volatile("" : "+a"(wt[i][kt]));
    }
  }

  // --- seq / steps ---------------------------------------------------------
  int seq4[4];
#pragma unroll
  for (int r = 0; r < 4; ++r) seq4[r] = seq[rg * RPB + quad * 4 + r];
  int Smax = 0;
#pragma unroll
  for (int i = 0; i < 16; ++i) Smax = max(Smax, seq[rg * RPB + i]);
  int steps = Smax - t0;
  if (steps < 0) steps = 0;
  if (steps > tc) steps = tc;

  // --- frag addressing -----------------------------------------------------
  // write pos (this thread's (row=quad*4+r, k=w*32+s*16+l15)):
  //   wbase + s*256 + r*64 (halfwords)
  const int wbase = (w * 64 + quad * 2 + (l15 >> 3)) * 8 + (l15 & 7);
  // read pos (A-frag for lane (quad,l15), ktile kt): kt*512 + rbase
  const int rbase = (((quad >> 1) << 5) + ((l15 & 3) << 3) +
                     ((l15 >> 2) << 1) + (quad & 1)) * 8;

  // --- h_reg init + h frag fill -------------------------------------------
  float h_reg[2][4];
#pragma unroll
  for (int s = 0; s < 2; ++s)
#pragma unroll
    for (int r = 0; r < 4; ++r) {
      int row = quad * 4 + r, k = w * 32 + s * 16 + l15;
      float v = (t0 == 0) ? 0.f : state[(size_t)(rg * RPB + row) * H_ + k];
      h_reg[s][r] = v;
      hpk[wbase + s * 256 + r * 64] = (_Float16)v;
    }

  // --- async G staging (time-major G; 16B/lane, wave-uniform LDS base) ----
  const float* gblk = G + (size_t)rg * RPB * NG;
  auto stage = [&](int t, int buf) {
    const float* gp = gblk + (size_t)t * BATCH * NG;
#pragma unroll
    for (int i = 0; i < 6; ++i) {
      int seg = w * 6 + i;                           // 0..47
      int rr = seg / 3, part = seg - rr * 3;
      const float* gsrc = gp + (size_t)seg * 256 + lane * 4;
      __builtin_amdgcn_global_load_lds(
          (const __attribute__((address_space(1))) unsigned int*)gsrc,
          (__attribute__((address_space(3))) unsigned int*)&Gs[buf][rr][part * 256],
          16, 0, 0);
    }
  };
  if (steps > 0) stage(0, 0);
  __syncthreads();

  for (int t = 0; t < steps; ++t) {
    const int buf = t & 1;
    // re-pin weights so VGPR copies can't be hoisted out of the loop
#pragma unroll
    for (int i = 0; i < 6; ++i)
#pragma unroll
      for (int kt = 0; kt < 8; ++kt)
        asm volatile("" : "+a"(wt[i][kt]));
    if (t + 1 < steps) stage(t + 1, buf ^ 1);   // async prefetch next G

    // ---------------- phase A: 4 gate tiles (r s=0,1 ; u s=0,1) ----------
    floatx4 acc[4] = {};
#pragma unroll
    for (int kt = 0; kt < 8; ++kt) {
      half8 a = *(const half8*)&hpk[kt * 512 + rbase];
#pragma unroll
      for (int s = 0; s < 4; ++s)
        acc[s] = __builtin_amdgcn_mfma_f32_16x16x32_f16(
            a, __builtin_bit_cast(half8, wt[s][kt]), acc[s], 0, 0, 0);
    }
#pragma unroll
    for (int s = 0; s < 2; ++s) {
      const int k = w * 32 + s * 16 + l15;
#pragma unroll
      for (int r = 0; r < 4; ++r) {
        int row = quad * 4 + r;
        float pre = acc[s][r] + Gs[buf][row][k];
        float g = __builtin_amdgcn_rcpf(1.f + __expf(-pre));
        rpk[wbase + s * 256 + r * 64] = (_Float16)(g * h_reg[s][r]);
      }
    }
    float u_reg[2][4];
#pragma unroll
    for (int s = 0; s < 2; ++s) {
      const int k = w * 32 + s * 16 + l15;
#pragma unroll
      for (int r = 0; r < 4; ++r) {
        int row = quad * 4 + r;
        float pre = acc[2 + s][r] + Gs[buf][row][256 + k];
        u_reg[s][r] = __builtin_amdgcn_rcpf(1.f + __expf(-pre));
      }
    }
    __syncthreads();
    // ---------------- phase B: 2 candidate tiles --------------------------
    floatx4 accB[2] = {};
#pragma unroll
    for (int kt = 0; kt < 8; ++kt) {
      half8 a = *(const half8*)&rpk[kt * 512 + rbase];
#pragma unroll
      for (int s = 0; s < 2; ++s)
        accB[s] = __builtin_amdgcn_mfma_f32_16x16x32_f16(
            a, __builtin_bit_cast(half8, wt[4 + s][kt]), accB[s], 0, 0, 0);
    }
#pragma unroll
    for (int s = 0; s < 2; ++s) {
      const int k = w * 32 + s * 16 + l15;
#pragma unroll
      for (int r = 0; r < 4; ++r) {
        int row = quad * 4 + r;
        float pre = accB[s][r] + Gs[buf][row][512 + k];
        float c = 1.f - 2.f * __builtin_amdgcn_rcpf(1.f + __expf(2.f * pre));
        float u = u_reg[s][r];
        float hn = u * h_reg[s][r] + (1.f - u) * c;
        bool valid = (t0 + t) < seq4[r];
        hn = valid ? hn : h_reg[s][r];
        h_reg[s][r] = hn;
        hpk[wbase + s * 256 + r * 64] = (_Float16)hn;
        if (outp)
          outp[((size_t)(rg * RPB + row) * tc + t) * H_ + k] = valid ? hn : 0.f;
      }
    }
    __syncthreads();
  }
  // --- save state from fp32 masters ---------------------------------------
#pragma unroll
  for (int s = 0; s < 2; ++s)
#pragma unroll
    for (int r = 0; r < 4; ++r)
      state[(size_t)(rg * RPB + quad * 4 + r) * H_ + (w * 32 + s * 16 + l15)] =
          h_reg[s][r];
}

// ---------------------------------------------------------------------------
// Final prediction: out[b, c] = [h_head | h_body] @ W_pred + b_pred.
// ---------------------------------------------------------------------------
__global__ __launch_bounds__(512) void pred_k(
    const float* __restrict__ hh, const float* __restrict__ hb,
    const float* __restrict__ Wp, const float* __restrict__ bpred,
    float* __restrict__ out)
{
  int tid = threadIdx.x;
  int b = tid >> 2, c = tid & 3;
  float acc = bpred[c];
  for (int k = 0; k < H_; ++k) acc += hh[b * H_ + k] * Wp[k * 4 + c];
  for (int k = 0; k < H_; ++k) acc += hb[b * H_ + k] * Wp[(H_ + k) * 4 + c];
  out[b * 4 + c] = acc;
}

// ---------------------------------------------------------------------------
extern "C" void kernel_launch(void* const* d_in, const int* in_sizes, int n_in,
                              void* d_out, int out_size, void* d_ws, size_t ws_size,
                              hipStream_t stream)
{
  (void)in_sizes; (void)n_in; (void)out_size;
  const int*   idsH = (const int*)  d_in[0];
  const int*   idsB = (const int*)  d_in[1];
  const float* emb  = (const float*)d_in[2];
  const float* Wp   = (const float*)d_in[3];
  const float* bp   = (const float*)d_in[4];
  const float* W[4][4];   // [hd0,hd1,bd0,bd1][Wg,bg,Wc,bc]
  for (int s = 0; s < 4; ++s)
    for (int q = 0; q < 4; ++q)
      W[s][q] = (const float*)d_in[5 + s * 4 + q];

  // choose time-chunk CH to fit ws_size (two G buffers for the pipeline)
  const size_t fixed_f = 1600000;
  int CH = 64;
  while (CH > 8 && (fixed_f + (size_t)BATCH * CH * (2 * NG + H_)) * 4 > ws_size)
    CH >>= 1;
  const int CHH = (CH < TH_) ? CH : TH_;

  float* wbase = (float*)d_ws;
  size_t off = 0;
  auto alloc = [&](size_t n) {
    float* p = wbase + off; off += (n + 255) & ~(size_t)255; return p;
  };
  int* seqH = (int*)alloc(BATCH);
  int* seqB = (int*)alloc(BATCH);
  float* Bx[4]; float* bi[4]; _Float16* Wpk[4];
  const int din[4] = {E_, H_, E_, H_};
  for (int s = 0; s < 4; ++s) {
    Bx[s]  = alloc((size_t)din[s] * NG);
    bi[s]  = alloc(NG);
    Wpk[s] = (_Float16*)alloc(48 * 8 * 64 * 8 / 2);   // 384 KB fp16
  }
  float* st0 = alloc((size_t)BATCH * H_);   // layer-0 carry (per stream, reused)
  float* hfH = alloc((size_t)BATCH * H_);   // head layer-1 carry/final
  float* hfB = alloc((size_t)BATCH * H_);   // body layer-1 carry/final
  float* Gc0 = alloc((size_t)BATCH * CH * NG);
  float* Gc1 = alloc((size_t)BATCH * CH * NG);
  float* Oc  = alloc((size_t)BATCH * CH * H_);
  (void)ws_size;

  // 1. pack weights
  for (int s = 0; s < 4; ++s) {
    int tot = din[s] * NG;
    pack_k<<<(tot + 255) / 256, 256, 0, stream>>>(
        W[s][0], W[s][1], W[s][2], W[s][3], din[s], Bx[s], bi[s]);
    pack_w<<<(48 * 64 + 255) / 256, 256, 0, stream>>>(
        W[s][0], W[s][2], din[s], Wpk[s]);
  }
  // 2. seqlens
  seq_k<<<BATCH, 256, 0, stream>>>(idsH, TH_, seqH);
  seq_k<<<BATCH, 256, 0, stream>>>(idsB, TB_, seqB);

  // 3. chunk-pipelined stream: fused dispatch runs L0(c) and L1(c-1)
  auto run_stream = [&](const int* ids, int T, int chs, const int* seq,
                        int l0, int l1, float* hf) {
    int nchunks = T / chs;
    int rows = BATCH * chs;
    dim3 g(rows / 64, NG / 64);
    for (int c = 0; c < nchunks; ++c) {
      int t0 = c * chs;
      gemm_in<<<g, 256, 0, stream>>>(nullptr, ids, emb, Bx[l0], bi[l0], Gc0,
                                     rows, E_, t0, chs, T);
      gru_pers<<<2 * NBLK, 512, 0, stream>>>(
          Gc0, Wpk[l0], seq, Oc, st0, t0, chs,
          (c > 0) ? Gc1 : nullptr, Wpk[l1], hf, (c - 1) * chs);
      gemm_in<<<g, 256, 0, stream>>>(Oc, nullptr, nullptr, Bx[l1], bi[l1], Gc1,
                                     rows, H_, 0, chs, T);
    }
    // drain: last layer-1 chunk
    gru_pers<<<2 * NBLK, 512, 0, stream>>>(
        nullptr, Wpk[l0], seq, nullptr, st0, 0, chs,
        Gc1, Wpk[l1], hf, (nchunks - 1) * chs);
  };
  run_stream(idsH, TH_, CHH, seqH, 0, 1, hfH);   // headline (hd0, hd1)
  run_stream(idsB, TB_, CH,  seqB, 2, 3, hfB);   // body     (bd0, bd1)

  // 4. prediction head
  pred_k<<<1, 512, 0, stream>>>(hfH, hfB, Wp, bp, (float*)d_out);
}

// Round 8
// 4731.417 us; speedup vs baseline: 1.4463x; 1.3812x over previous
//
#include <hip/hip_runtime.h>
#include <cstdint>
#include <cstddef>

// Problem constants: V=50000, E=300, NF=1, H=256, B=128, TH=32, TB=512, NC=4.
#define H_    256
#define NG    768      // 512 gate cols (r|u) + 256 candidate cols, packed
#define BATCH 128
#define TH_   32
#define TB_   512
#define E_    300
#define RPB   16             // batch rows per gru block
#define NBLK  (BATCH / RPB)  // 8 row-groups; fused grid = 16 blocks

typedef _Float16 half8 __attribute__((ext_vector_type(8)));
typedef float    floatx4 __attribute__((ext_vector_type(4)));

// s_waitcnt immediates (gfx9 encoding: vmcnt[3:0]=imm[3:0], vmcnt[5:4]=imm[15:14],
// expcnt=imm[6:4], lgkmcnt=imm[11:8]).
#define WC_LGKM0 0xC07F   // lgkmcnt(0), vmcnt/exp unconstrained
#define WC_VM14  0x0F7E   // vmcnt(14) only
#define WC_VM6   0x0F76   // vmcnt(6)  only
#define WC_VM0   0x0F70   // vmcnt(0)  only

// ---------------------------------------------------------------------------
// Pack input-projection weights (fp32) + bias. j<512 -> Wg col j; else Wc.
// ---------------------------------------------------------------------------
__global__ __launch_bounds__(256) void pack_k(
    const float* __restrict__ Wg, const float* __restrict__ bg,
    const float* __restrict__ Wc, const float* __restrict__ bc, int din,
    float* __restrict__ Bx, float* __restrict__ bias)
{
  int idx = blockIdx.x * 256 + threadIdx.x;
  if (idx < NG) bias[idx] = (idx < 2 * H_) ? bg[idx] : bc[idx - 2 * H_];
  int tot = din * NG;
  if (idx >= tot) return;
  int k = idx / NG, j = idx % NG;
  float v = (j < 2 * H_) ? Wg[k * 2 * H_ + j] : Wc[k * H_ + (j - 2 * H_)];
  Bx[(size_t)k * NG + j] = v;
}

// ---------------------------------------------------------------------------
// Pack recurrent weights into fp16 MFMA B-fragment order, retiled for the
// per-wave column assignment of gru_pers (R7-validated):
//   tiles [0,16):  r-gates,  tile = w*2+s -> Wg col n0 = w*32+s*16
//   tiles [16,32): u-gates,  Wg col n0 = 256 + w*32+s*16
//   tiles [32,48): candidate, Wc col n0 = w*32+s*16
// B-frag: lane l, elem j -> W[din + kt*32 + (l>>4)*8 + j][n0 + (l&15)]
// ---------------------------------------------------------------------------
__global__ __launch_bounds__(256) void pack_w(
    const float* __restrict__ Wg, const float* __restrict__ Wc, int din,
    _Float16* __restrict__ wpk)
{
  int idx = blockIdx.x * 256 + threadIdx.x;
  if (idx >= 48 * 64) return;
  int tile = idx >> 6, lane = idx & 63;
  int grp = tile >> 4, tt = tile & 15;
  int wv = tt >> 1, s = tt & 1;
  const float* W; int ncols, n0;
  if (grp == 0)      { W = Wg; ncols = 2 * H_; n0 = wv * 32 + s * 16; }
  else if (grp == 1) { W = Wg; ncols = 2 * H_; n0 = 256 + wv * 32 + s * 16; }
  else               { W = Wc; ncols = H_;     n0 = wv * 32 + s * 16; }
  int n = n0 + (lane & 15);
  int kb = (lane >> 4) * 8;
#pragma unroll
  for (int kt = 0; kt < 8; ++kt) {
    _Float16* dst = wpk + ((size_t)(tile * 8 + kt) * 64 + lane) * 8;
#pragma unroll
    for (int j = 0; j < 8; ++j)
      dst[j] = (_Float16)W[(size_t)(din + kt * 32 + kb + j) * ncols + n];
  }
}

// ---------------------------------------------------------------------------
// seqlen[b] = #nonzero ids in row b (valid steps form a prefix).
// ---------------------------------------------------------------------------
__global__ __launch_bounds__(256) void seq_k(const int* __restrict__ ids, int T,
                                             int* __restrict__ seq)
{
  __shared__ int red[256];
  int b = blockIdx.x, tid = threadIdx.x;
  int cnt = 0;
  for (int t = tid; t < T; t += 256) cnt += (ids[b * T + t] != 0) ? 1 : 0;
  red[tid] = cnt;
  __syncthreads();
  for (int s = 128; s > 0; s >>= 1) {
    if (tid < s) red[tid] += red[tid + s];
    __syncthreads();
  }
  if (tid == 0) seq[b] = red[0];
}

// ---------------------------------------------------------------------------
// Input-projection GEMM over a time-chunk (fp32):
//   G[(tl*BATCH + b)*NG + col] = A[row, :K] @ Bp[K, 768] + bias,
//   row = b*tc + tl (time-major G output for the persistent gru).
// ---------------------------------------------------------------------------
__global__ __launch_bounds__(256) void gemm_in(
    const float* __restrict__ Adir, const int* __restrict__ ids,
    const float* __restrict__ emb,
    const float* __restrict__ Bp, const float* __restrict__ bias,
    float* __restrict__ G, int nrows, int K, int t0, int tc, int T)
{
  __shared__ float As[16][68];
  __shared__ float Bs[16][64];
  const int tid = threadIdx.x;
  const int m0 = blockIdx.x * 64;
  const int n0 = blockIdx.y * 64;
  const int tm = (tid >> 4) * 4;
  const int tn = (tid & 15) * 4;
  const int la_r = tid >> 4;
  const int la_k = tid & 15;
  const int lb_n = tid & 63;
  const int lb_k = tid >> 6;
  float acc[4][4] = {{0.f}};

  for (int k0 = 0; k0 < K; k0 += 16) {
#pragma unroll
    for (int p = 0; p < 4; ++p) {
      int r = p * 16 + la_r;
      int row = m0 + r;
      int kg = k0 + la_k;
      float v = 0.f;
      if (row < nrows && kg < K) {
        if (Adir) v = Adir[(size_t)row * K + kg];
        else {
          int b = row / tc, tl = row % tc;
          v = emb[(size_t)ids[b * T + t0 + tl] * K + kg];
        }
      }
      As[la_k][r] = v;
    }
#pragma unroll
    for (int p = 0; p < 4; ++p) {
      int kl = p * 4 + lb_k;
      int kg = k0 + kl;
      Bs[kl][lb_n] = (kg < K) ? Bp[(size_t)kg * NG + n0 + lb_n] : 0.f;
    }
    __syncthreads();
#pragma unroll
    for (int kk = 0; kk < 16; ++kk) {
      float a0 = As[kk][tm + 0], a1 = As[kk][tm + 1];
      float a2 = As[kk][tm + 2], a3 = As[kk][tm + 3];
      float b0 = Bs[kk][tn + 0], b1 = Bs[kk][tn + 1];
      float b2 = Bs[kk][tn + 2], b3 = Bs[kk][tn + 3];
      acc[0][0] += a0 * b0; acc[0][1] += a0 * b1; acc[0][2] += a0 * b2; acc[0][3] += a0 * b3;
      acc[1][0] += a1 * b0; acc[1][1] += a1 * b1; acc[1][2] += a1 * b2; acc[1][3] += a1 * b3;
      acc[2][0] += a2 * b0; acc[2][1] += a2 * b1; acc[2][2] += a2 * b2; acc[2][3] += a2 * b3;
      acc[3][0] += a3 * b0; acc[3][1] += a3 * b1; acc[3][2] += a3 * b2; acc[3][3] += a3 * b3;
    }
    __syncthreads();
  }
#pragma unroll
  for (int i = 0; i < 4; ++i) {
    int row = m0 + tm + i;
    if (row < nrows) {
      int b = row / tc, tl = row - b * tc;
      float* gout = G + ((size_t)tl * BATCH + b) * NG + n0 + tn;
#pragma unroll
      for (int j = 0; j < 4; ++j)
        gout[j] = acc[i][j] + bias[n0 + tn + j];
    }
  }
}

// ---------------------------------------------------------------------------
// Persistent-weight fused GRU. Grid = 16 blocks x 512 thr, 1 block/CU.
// R8 changes vs R7 (structure/layout identical otherwise):
//  * weights pinned into AGPRs ONCE before the loop (asm output can't be
//    rematerialized -> loads can't sink back into the loop; no per-step asm).
//  * raw s_barrier with minimal s_waitcnt instead of __syncthreads():
//    barriers drain lgkmcnt only (LDS visibility). The G prefetch is waited
//    with a precise vmcnt(N) right before the epilogue reads it (N = ops
//    issued since those loads: 14 with outp stores in flight, 6 without,
//    0 on the final step). outp stores are NEVER drained in-kernel (the
//    dispatch boundary orders them before the consumer gemm).
// ---------------------------------------------------------------------------
__global__ __launch_bounds__(512, 1) void gru_pers(
    const float* __restrict__ G0, const _Float16* __restrict__ W0,
    const int* __restrict__ seq, float* __restrict__ out0,
    float* __restrict__ st0, int t00, int tc,
    const float* __restrict__ G1, const _Float16* __restrict__ W1,
    float* __restrict__ st1, int t01)
{
  __shared__ __align__(16) _Float16 hpk[4096];    // h frags (fp16)
  __shared__ __align__(16) _Float16 rpk[4096];    // r*h frags (fp16)
  __shared__ __align__(16) float Gs[2][16][772];  // staged G, padded rows

  const int bid = blockIdx.x;
  const float* G; const _Float16* Wsrc; float* outp; float* state; int t0, rg;
  if (bid < NBLK) { G = G0; Wsrc = W0; outp = out0; state = st0; t0 = t00; rg = bid; }
  else            { G = G1; Wsrc = W1; outp = nullptr; state = st1; t0 = t01; rg = bid - NBLK; }
  if (!G) return;

  const int tid = threadIdx.x;
  const int w = tid >> 6, lane = tid & 63;
  const int quad = lane >> 4, l15 = lane & 15;

  // --- load weights once; pin into AGPRs once (blocks rematerialization) --
  floatx4 wt[6][8];
#pragma unroll
  for (int i = 0; i < 6; ++i) {
    const int tile = (i >> 1) * 16 + w * 2 + (i & 1);
#pragma unroll
    for (int kt = 0; kt < 8; ++kt) {
      wt[i][kt] = *(const floatx4*)&Wsrc[((size_t)(tile * 8 + kt) * 64 + lane) * 8];
      asm volatile("" : "+a"(wt[i][kt]));
    }
  }

  // --- seq / steps ---------------------------------------------------------
  int seq4[4];
#pragma unroll
  for (int r = 0; r < 4; ++r) seq4[r] = seq[rg * RPB + quad * 4 + r];
  int Smax = 0;
#pragma unroll
  for (int i = 0; i < 16; ++i) Smax = max(Smax, seq[rg * RPB + i]);
  int steps = Smax - t0;
  if (steps < 0) steps = 0;
  if (steps > tc) steps = tc;

  // --- frag addressing (R7-validated bank-exact layout) --------------------
  const int wbase = (w * 64 + quad * 2 + (l15 >> 3)) * 8 + (l15 & 7);
  const int rbase = (((quad >> 1) << 5) + ((l15 & 3) << 3) +
                     ((l15 >> 2) << 1) + (quad & 1)) * 8;

  // --- h_reg init + h frag fill -------------------------------------------
  float h_reg[2][4];
#pragma unroll
  for (int s = 0; s < 2; ++s)
#pragma unroll
    for (int r = 0; r < 4; ++r) {
      int row = quad * 4 + r, k = w * 32 + s * 16 + l15;
      float v = (t0 == 0) ? 0.f : state[(size_t)(rg * RPB + row) * H_ + k];
      h_reg[s][r] = v;
      hpk[wbase + s * 256 + r * 64] = (_Float16)v;
    }

  // --- async G staging (time-major G; 16B/lane, wave-uniform LDS base) ----
  const float* gblk = G + (size_t)rg * RPB * NG;
  auto stage = [&](int t, int buf) {
    const float* gp = gblk + (size_t)t * BATCH * NG;
#pragma unroll
    for (int i = 0; i < 6; ++i) {
      int seg = w * 6 + i;                           // 0..47
      int rr = seg / 3, part = seg - rr * 3;
      const float* gsrc = gp + (size_t)seg * 256 + lane * 4;
      __builtin_amdgcn_global_load_lds(
          (const __attribute__((address_space(1))) unsigned int*)gsrc,
          (__attribute__((address_space(3))) unsigned int*)&Gs[buf][rr][part * 256],
          16, 0, 0);
    }
  };
  if (steps > 0) stage(0, 0);
  __syncthreads();   // one full drain: L_0 complete + hpk visible

  for (int t = 0; t < steps; ++t) {
    const int buf = t & 1;
    const bool staged = (t + 1 < steps);
    if (staged) stage(t + 1, buf ^ 1);   // async prefetch next step's G

    // ---------------- phase A: 4 gate tiles (r s=0,1 ; u s=0,1) ----------
    floatx4 acc[4] = {};
#pragma unroll
    for (int kt = 0; kt < 8; ++kt) {
      half8 a = *(const half8*)&hpk[kt * 512 + rbase];
#pragma unroll
      for (int s = 0; s < 4; ++s)
        acc[s] = __builtin_amdgcn_mfma_f32_16x16x32_f16(
            a, __builtin_bit_cast(half8, wt[s][kt]), acc[s], 0, 0, 0);
    }

    // wait ONLY for this step's 6 G loads (issued last iteration); never
    // drain the outp stores.
    if (staged) {
      if (outp) __builtin_amdgcn_s_waitcnt(WC_VM14);
      else      __builtin_amdgcn_s_waitcnt(WC_VM6);
    } else {
      __builtin_amdgcn_s_waitcnt(WC_VM0);
    }

#pragma unroll
    for (int s = 0; s < 2; ++s) {
      const int k = w * 32 + s * 16 + l15;
#pragma unroll
      for (int r = 0; r < 4; ++r) {
        int row = quad * 4 + r;
        float pre = acc[s][r] + Gs[buf][row][k];
        float g = __builtin_amdgcn_rcpf(1.f + __expf(-pre));
        rpk[wbase + s * 256 + r * 64] = (_Float16)(g * h_reg[s][r]);
      }
    }
    float u_reg[2][4];
#pragma unroll
    for (int s = 0; s < 2; ++s) {
      const int k = w * 32 + s * 16 + l15;
#pragma unroll
      for (int r = 0; r < 4; ++r) {
        int row = quad * 4 + r;
        float pre = acc[2 + s][r] + Gs[buf][row][256 + k];
        u_reg[s][r] = __builtin_amdgcn_rcpf(1.f + __expf(-pre));
      }
    }
    __builtin_amdgcn_s_waitcnt(WC_LGKM0);   // rpk visible
    __builtin_amdgcn_s_barrier();

    // ---------------- phase B: 2 candidate tiles --------------------------
    floatx4 accB[2] = {};
#pragma unroll
    for (int kt = 0; kt < 8; ++kt) {
      half8 a = *(const half8*)&rpk[kt * 512 + rbase];
#pragma unroll
      for (int s = 0; s < 2; ++s)
        accB[s] = __builtin_amdgcn_mfma_f32_16x16x32_f16(
            a, __builtin_bit_cast(half8, wt[4 + s][kt]), accB[s], 0, 0, 0);
    }
#pragma unroll
    for (int s = 0; s < 2; ++s) {
      const int k = w * 32 + s * 16 + l15;
#pragma unroll
      for (int r = 0; r < 4; ++r) {
        int row = quad * 4 + r;
        float pre = accB[s][r] + Gs[buf][row][512 + k];
        float c = 1.f - 2.f * __builtin_amdgcn_rcpf(1.f + __expf(2.f * pre));
        float u = u_reg[s][r];
        float hn = u * h_reg[s][r] + (1.f - u) * c;
        bool valid = (t0 + t) < seq4[r];
        hn = valid ? hn : h_reg[s][r];
        h_reg[s][r] = hn;
        hpk[wbase + s * 256 + r * 64] = (_Float16)hn;
        if (outp)
          outp[((size_t)(rg * RPB + row) * tc + t) * H_ + k] = valid ? hn : 0.f;
      }
    }
    __builtin_amdgcn_s_waitcnt(WC_LGKM0);   // hpk visible
    __builtin_amdgcn_s_barrier();
  }
  // --- save state from fp32 masters ---------------------------------------
#pragma unroll
  for (int s = 0; s < 2; ++s)
#pragma unroll
    for (int r = 0; r < 4; ++r)
      state[(size_t)(rg * RPB + quad * 4 + r) * H_ + (w * 32 + s * 16 + l15)] =
          h_reg[s][r];
}

// ---------------------------------------------------------------------------
// Final prediction: out[b, c] = [h_head | h_body] @ W_pred + b_pred.
// ---------------------------------------------------------------------------
__global__ __launch_bounds__(512) void pred_k(
    const float* __restrict__ hh, const float* __restrict__ hb,
    const float* __restrict__ Wp, const float* __restrict__ bpred,
    float* __restrict__ out)
{
  int tid = threadIdx.x;
  int b = tid >> 2, c = tid & 3;
  float acc = bpred[c];
  for (int k = 0; k < H_; ++k) acc += hh[b * H_ + k] * Wp[k * 4 + c];
  for (int k = 0; k < H_; ++k) acc += hb[b * H_ + k] * Wp[(H_ + k) * 4 + c];
  out[b * 4 + c] = acc;
}

// ---------------------------------------------------------------------------
extern "C" void kernel_launch(void* const* d_in, const int* in_sizes, int n_in,
                              void* d_out, int out_size, void* d_ws, size_t ws_size,
                              hipStream_t stream)
{
  (void)in_sizes; (void)n_in; (void)out_size;
  const int*   idsH = (const int*)  d_in[0];
  const int*   idsB = (const int*)  d_in[1];
  const float* emb  = (const float*)d_in[2];
  const float* Wp   = (const float*)d_in[3];
  const float* bp   = (const float*)d_in[4];
  const float* W[4][4];   // [hd0,hd1,bd0,bd1][Wg,bg,Wc,bc]
  for (int s = 0; s < 4; ++s)
    for (int q = 0; q < 4; ++q)
      W[s][q] = (const float*)d_in[5 + s * 4 + q];

  // choose time-chunk CH to fit ws_size (two G buffers for the pipeline)
  const size_t fixed_f = 1600000;
  int CH = 64;
  while (CH > 8 && (fixed_f + (size_t)BATCH * CH * (2 * NG + H_)) * 4 > ws_size)
    CH >>= 1;
  const int CHH = (CH < TH_) ? CH : TH_;

  float* wbase = (float*)d_ws;
  size_t off = 0;
  auto alloc = [&](size_t n) {
    float* p = wbase + off; off += (n + 255) & ~(size_t)255; return p;
  };
  int* seqH = (int*)alloc(BATCH);
  int* seqB = (int*)alloc(BATCH);
  float* Bx[4]; float* bi[4]; _Float16* Wpk[4];
  const int din[4] = {E_, H_, E_, H_};
  for (int s = 0; s < 4; ++s) {
    Bx[s]  = alloc((size_t)din[s] * NG);
    bi[s]  = alloc(NG);
    Wpk[s] = (_Float16*)alloc(48 * 8 * 64 * 8 / 2);   // 384 KB fp16
  }
  float* st0 = alloc((size_t)BATCH * H_);   // layer-0 carry (per stream, reused)
  float* hfH = alloc((size_t)BATCH * H_);   // head layer-1 carry/final
  float* hfB = alloc((size_t)BATCH * H_);   // body layer-1 carry/final
  float* Gc0 = alloc((size_t)BATCH * CH * NG);
  float* Gc1 = alloc((size_t)BATCH * CH * NG);
  float* Oc  = alloc((size_t)BATCH * CH * H_);
  (void)ws_size;

  // 1. pack weights
  for (int s = 0; s < 4; ++s) {
    int tot = din[s] * NG;
    pack_k<<<(tot + 255) / 256, 256, 0, stream>>>(
        W[s][0], W[s][1], W[s][2], W[s][3], din[s], Bx[s], bi[s]);
    pack_w<<<(48 * 64 + 255) / 256, 256, 0, stream>>>(
        W[s][0], W[s][2], din[s], Wpk[s]);
  }
  // 2. seqlens
  seq_k<<<BATCH, 256, 0, stream>>>(idsH, TH_, seqH);
  seq_k<<<BATCH, 256, 0, stream>>>(idsB, TB_, seqB);

  // 3. chunk-pipelined stream: fused dispatch runs L0(c) and L1(c-1)
  auto run_stream = [&](const int* ids, int T, int chs, const int* seq,
                        int l0, int l1, float* hf) {
    int nchunks = T / chs;
    int rows = BATCH * chs;
    dim3 g(rows / 64, NG / 64);
    for (int c = 0; c < nchunks; ++c) {
      int t0 = c * chs;
      gemm_in<<<g, 256, 0, stream>>>(nullptr, ids, emb, Bx[l0], bi[l0], Gc0,
                                     rows, E_, t0, chs, T);
      gru_pers<<<2 * NBLK, 512, 0, stream>>>(
          Gc0, Wpk[l0], seq, Oc, st0, t0, chs,
          (c > 0) ? Gc1 : nullptr, Wpk[l1], hf, (c - 1) * chs);
      gemm_in<<<g, 256, 0, stream>>>(Oc, nullptr, nullptr, Bx[l1], bi[l1], Gc1,
                                     rows, H_, 0, chs, T);
    }
    // drain: last layer-1 chunk
    gru_pers<<<2 * NBLK, 512, 0, stream>>>(
        nullptr, Wpk[l0], seq, nullptr, st0, 0, chs,
        Gc1, Wpk[l1], hf, (nchunks - 1) * chs);
  };
  run_stream(idsH, TH_, CHH, seqH, 0, 1, hfH);   // headline (hd0, hd1)
  run_stream(idsB, TB_, CH,  seqB, 2, 3, hfB);   // body     (bd0, bd1)

  // 4. prediction head
  pred_k<<<1, 512, 0, stream>>>(hfH, hfB, Wp, bp, (float*)d_out);
}

// Round 9
// 4649.088 us; speedup vs baseline: 1.4719x; 1.0177x over previous
//
#include <hip/hip_runtime.h>
#include <cstdint>
#include <cstddef>

// Problem constants: V=50000, E=300, NF=1, H=256, B=128, TH=32, TB=512, NC=4.
#define H_    256
#define NG    768      // 512 gate cols (r|u) + 256 candidate cols, packed
#define BATCH 128
#define TH_   32
#define TB_   512
#define E_    300
#define RPB   16             // batch rows per gru block
#define NBLK  (BATCH / RPB)  // 8 row-groups; fused grid = 16 blocks

typedef _Float16 half8 __attribute__((ext_vector_type(8)));
typedef float    floatx4 __attribute__((ext_vector_type(4)));

// s_waitcnt immediates (gfx9 encoding: vmcnt[3:0]=imm[3:0], vmcnt[5:4]=imm[15:14],
// expcnt=imm[6:4], lgkmcnt=imm[11:8]).
#define WC_LGKM0 0xC07F   // lgkmcnt(0), vmcnt/exp unconstrained
#define WC_VM14  0x0F7E   // vmcnt(14) only
#define WC_VM6   0x0F76   // vmcnt(6)  only
#define WC_VM0   0x0F70   // vmcnt(0)  only

// ---------------------------------------------------------------------------
// Pack input-projection weights (fp32) + bias. j<512 -> Wg col j; else Wc.
// ---------------------------------------------------------------------------
__global__ __launch_bounds__(256) void pack_k(
    const float* __restrict__ Wg, const float* __restrict__ bg,
    const float* __restrict__ Wc, const float* __restrict__ bc, int din,
    float* __restrict__ Bx, float* __restrict__ bias)
{
  int idx = blockIdx.x * 256 + threadIdx.x;
  if (idx < NG) bias[idx] = (idx < 2 * H_) ? bg[idx] : bc[idx - 2 * H_];
  int tot = din * NG;
  if (idx >= tot) return;
  int k = idx / NG, j = idx % NG;
  float v = (j < 2 * H_) ? Wg[k * 2 * H_ + j] : Wc[k * H_ + (j - 2 * H_)];
  Bx[(size_t)k * NG + j] = v;
}

// ---------------------------------------------------------------------------
// Pack recurrent weights into fp16 MFMA B-fragment order, retiled for the
// per-wave column assignment of gru_pers (R7-validated):
//   tiles [0,16):  r-gates,  tile = w*2+s -> Wg col n0 = w*32+s*16
//   tiles [16,32): u-gates,  Wg col n0 = 256 + w*32+s*16
//   tiles [32,48): candidate, Wc col n0 = w*32+s*16
// B-frag: lane l, elem j -> W[din + kt*32 + (l>>4)*8 + j][n0 + (l&15)]
// ---------------------------------------------------------------------------
__global__ __launch_bounds__(256) void pack_w(
    const float* __restrict__ Wg, const float* __restrict__ Wc, int din,
    _Float16* __restrict__ wpk)
{
  int idx = blockIdx.x * 256 + threadIdx.x;
  if (idx >= 48 * 64) return;
  int tile = idx >> 6, lane = idx & 63;
  int grp = tile >> 4, tt = tile & 15;
  int wv = tt >> 1, s = tt & 1;
  const float* W; int ncols, n0;
  if (grp == 0)      { W = Wg; ncols = 2 * H_; n0 = wv * 32 + s * 16; }
  else if (grp == 1) { W = Wg; ncols = 2 * H_; n0 = 256 + wv * 32 + s * 16; }
  else               { W = Wc; ncols = H_;     n0 = wv * 32 + s * 16; }
  int n = n0 + (lane & 15);
  int kb = (lane >> 4) * 8;
#pragma unroll
  for (int kt = 0; kt < 8; ++kt) {
    _Float16* dst = wpk + ((size_t)(tile * 8 + kt) * 64 + lane) * 8;
#pragma unroll
    for (int j = 0; j < 8; ++j)
      dst[j] = (_Float16)W[(size_t)(din + kt * 32 + kb + j) * ncols + n];
  }
}

// ---------------------------------------------------------------------------
// seqlen[b] = #nonzero ids in row b (valid steps form a prefix).
// ---------------------------------------------------------------------------
__global__ __launch_bounds__(256) void seq_k(const int* __restrict__ ids, int T,
                                             int* __restrict__ seq)
{
  __shared__ int red[256];
  int b = blockIdx.x, tid = threadIdx.x;
  int cnt = 0;
  for (int t = tid; t < T; t += 256) cnt += (ids[b * T + t] != 0) ? 1 : 0;
  red[tid] = cnt;
  __syncthreads();
  for (int s = 128; s > 0; s >>= 1) {
    if (tid < s) red[tid] += red[tid + s];
    __syncthreads();
  }
  if (tid == 0) seq[b] = red[0];
}

// ---------------------------------------------------------------------------
// Input-projection GEMM over a time-chunk (fp32).
// OUTPUT LAYOUT (R9): fragment-packed for gru_pers. For (t, batch row b,
// col): rg=b>>4, m=b&15, quad=m>>2, r=m&3, g=col>>8, kk=col&255, w=kk>>5,
// s=(kk>>4)&1, l15=kk&15, chunk c=2g+s, lane=quad*16+l15:
//   G[(t*BATCH + rg*16)*768 + ((w*6+c)*64 + lane)*4 + r]
// so each gru thread's 24 G values are 6 contiguous float4s and each wave's
// step slice is a contiguous 6 KB span (global_load_lds-compatible).
// ---------------------------------------------------------------------------
__global__ __launch_bounds__(256) void gemm_in(
    const float* __restrict__ Adir, const int* __restrict__ ids,
    const float* __restrict__ emb,
    const float* __restrict__ Bp, const float* __restrict__ bias,
    float* __restrict__ G, int nrows, int K, int t0, int tc, int T)
{
  __shared__ float As[16][68];
  __shared__ float Bs[16][64];
  const int tid = threadIdx.x;
  const int m0 = blockIdx.x * 64;
  const int n0 = blockIdx.y * 64;
  const int tm = (tid >> 4) * 4;
  const int tn = (tid & 15) * 4;
  const int la_r = tid >> 4;
  const int la_k = tid & 15;
  const int lb_n = tid & 63;
  const int lb_k = tid >> 6;
  float acc[4][4] = {{0.f}};

  for (int k0 = 0; k0 < K; k0 += 16) {
#pragma unroll
    for (int p = 0; p < 4; ++p) {
      int r = p * 16 + la_r;
      int row = m0 + r;
      int kg = k0 + la_k;
      float v = 0.f;
      if (row < nrows && kg < K) {
        if (Adir) v = Adir[(size_t)row * K + kg];
        else {
          int b = row / tc, tl = row % tc;
          v = emb[(size_t)ids[b * T + t0 + tl] * K + kg];
        }
      }
      As[la_k][r] = v;
    }
#pragma unroll
    for (int p = 0; p < 4; ++p) {
      int kl = p * 4 + lb_k;
      int kg = k0 + kl;
      Bs[kl][lb_n] = (kg < K) ? Bp[(size_t)kg * NG + n0 + lb_n] : 0.f;
    }
    __syncthreads();
#pragma unroll
    for (int kk = 0; kk < 16; ++kk) {
      float a0 = As[kk][tm + 0], a1 = As[kk][tm + 1];
      float a2 = As[kk][tm + 2], a3 = As[kk][tm + 3];
      float b0 = Bs[kk][tn + 0], b1 = Bs[kk][tn + 1];
      float b2 = Bs[kk][tn + 2], b3 = Bs[kk][tn + 3];
      acc[0][0] += a0 * b0; acc[0][1] += a0 * b1; acc[0][2] += a0 * b2; acc[0][3] += a0 * b3;
      acc[1][0] += a1 * b0; acc[1][1] += a1 * b1; acc[1][2] += a1 * b2; acc[1][3] += a1 * b3;
      acc[2][0] += a2 * b0; acc[2][1] += a2 * b1; acc[2][2] += a2 * b2; acc[2][3] += a2 * b3;
      acc[3][0] += a3 * b0; acc[3][1] += a3 * b1; acc[3][2] += a3 * b2; acc[3][3] += a3 * b3;
    }
    __syncthreads();
  }
  // fragment-packed epilogue (scalar stores; cols j share w/s/g, vary l15)
#pragma unroll
  for (int i = 0; i < 4; ++i) {
    int row = m0 + tm + i;
    if (row < nrows) {
      int b = row / tc, tl = row - b * tc;
      int rg = b >> 4, mm = b & 15;
      int quad = mm >> 2, r = mm & 3;
      float* gbase = G + ((size_t)tl * BATCH + rg * RPB) * NG;
#pragma unroll
      for (int j = 0; j < 4; ++j) {
        int col = n0 + tn + j;
        int g = col >> 8, kk = col & 255;
        int ww = kk >> 5, s = (kk >> 4) & 1, ll = kk & 15;
        gbase[((ww * 6 + 2 * g + s) * 64 + quad * 16 + ll) * 4 + r] =
            acc[i][j] + bias[col];
      }
    }
  }
}

// ---------------------------------------------------------------------------
// Persistent-weight fused GRU. Grid = 16 blocks x 512 thr, 1 block/CU.
// R9 changes vs R8:
//  * gate weights (4 tiles, 128 regs) pinned "+v" (VGPR) — if MFMA needed
//    VGPR operands, the "+a" pins were costing ~192 v_accvgpr_reads/step;
//    candidate weights (2 tiles, 64 regs) stay "+a" to fit the 256/wave
//    unified budget (~188 arch + 64 acc).
//  * G is fragment-packed (see gemm_in): each wave stages its own 6 KB/step
//    via 6 global_load_lds; each thread reads its 24 G values as 6
//    ds_read_b128 (was 24 ds_read_b32 + addr math). Gs is wave-private.
//  * barriers stay minimal-wait (lgkm-only), G waited with precise vmcnt.
// ---------------------------------------------------------------------------
__global__ __launch_bounds__(512, 1) void gru_pers(
    const float* __restrict__ G0, const _Float16* __restrict__ W0,
    const int* __restrict__ seq, float* __restrict__ out0,
    float* __restrict__ st0, int t00, int tc,
    const float* __restrict__ G1, const _Float16* __restrict__ W1,
    float* __restrict__ st1, int t01)
{
  __shared__ __align__(16) _Float16 hpk[4096];    // h frags (fp16)
  __shared__ __align__(16) _Float16 rpk[4096];    // r*h frags (fp16)
  __shared__ __align__(16) float Gs[2][12288];    // staged G, wave-private

  const int bid = blockIdx.x;
  const float* G; const _Float16* Wsrc; float* outp; float* state; int t0, rg;
  if (bid < NBLK) { G = G0; Wsrc = W0; outp = out0; state = st0; t0 = t00; rg = bid; }
  else            { G = G1; Wsrc = W1; outp = nullptr; state = st1; t0 = t01; rg = bid - NBLK; }
  if (!G) return;

  const int tid = threadIdx.x;
  const int w = tid >> 6, lane = tid & 63;
  const int quad = lane >> 4, l15 = lane & 15;

  // --- load weights once; pin (blocks rematerialization/sinking) ----------
  floatx4 wg[4][8];   // gate tiles -> VGPRs
  floatx4 wc[2][8];   // candidate tiles -> AGPRs
#pragma unroll
  for (int i = 0; i < 4; ++i) {
    const int tile = (i >> 1) * 16 + w * 2 + (i & 1);
#pragma unroll
    for (int kt = 0; kt < 8; ++kt) {
      wg[i][kt] = *(const floatx4*)&Wsrc[((size_t)(tile * 8 + kt) * 64 + lane) * 8];
      asm volatile("" : "+v"(wg[i][kt]));
    }
  }
#pragma unroll
  for (int i = 0; i < 2; ++i) {
    const int tile = 32 + w * 2 + i;
#pragma unroll
    for (int kt = 0; kt < 8; ++kt) {
      wc[i][kt] = *(const floatx4*)&Wsrc[((size_t)(tile * 8 + kt) * 64 + lane) * 8];
      asm volatile("" : "+a"(wc[i][kt]));
    }
  }

  // --- seq / steps ---------------------------------------------------------
  int seq4[4];
#pragma unroll
  for (int r = 0; r < 4; ++r) seq4[r] = seq[rg * RPB + quad * 4 + r];
  int Smax = 0;
#pragma unroll
  for (int i = 0; i < 16; ++i) Smax = max(Smax, seq[rg * RPB + i]);
  int steps = Smax - t0;
  if (steps < 0) steps = 0;
  if (steps > tc) steps = tc;

  // --- frag addressing (R7-validated bank-exact layout) --------------------
  const int wbase = (w * 64 + quad * 2 + (l15 >> 3)) * 8 + (l15 & 7);
  const int rbase = (((quad >> 1) << 5) + ((l15 & 3) << 3) +
                     ((l15 >> 2) << 1) + (quad & 1)) * 8;

  // --- h_reg init + h frag fill -------------------------------------------
  float h_reg[2][4];
#pragma unroll
  for (int s = 0; s < 2; ++s)
#pragma unroll
    for (int r = 0; r < 4; ++r) {
      int row = quad * 4 + r, k = w * 32 + s * 16 + l15;
      float v = (t0 == 0) ? 0.f : state[(size_t)(rg * RPB + row) * H_ + k];
      h_reg[s][r] = v;
      hpk[wbase + s * 256 + r * 64] = (_Float16)v;
    }

  // --- async G staging: wave w copies its own 6 chunks (1 KB each) --------
  const float* gblk = G + (size_t)rg * RPB * NG + w * (6 * 256);
  float* ldsw = &Gs[0][0] + w * (6 * 256);
  auto stage = [&](int t, int buf) {
    const float* gp = gblk + (size_t)t * BATCH * NG;
    float* lp = ldsw + buf * 12288;
#pragma unroll
    for (int c = 0; c < 6; ++c) {
      __builtin_amdgcn_global_load_lds(
          (const __attribute__((address_space(1))) unsigned int*)(gp + c * 256 + lane * 4),
          (__attribute__((address_space(3))) unsigned int*)(lp + c * 256),
          16, 0, 0);
    }
  };
  if (steps > 0) stage(0, 0);
  __syncthreads();   // one full drain: loads for t=0 complete + hpk visible

  const _Float16* hA = &hpk[rbase];
  const _Float16* rA = &rpk[rbase];

  for (int t = 0; t < steps; ++t) {
    const int buf = t & 1;
    const bool staged = (t + 1 < steps);
    if (staged) stage(t + 1, buf ^ 1);   // async prefetch next step's G

    // ---------------- phase A: 4 gate tiles (r s=0,1 ; u s=0,1) ----------
    floatx4 acc[4] = {};
#pragma unroll
    for (int kt = 0; kt < 8; ++kt) {
      half8 a = *(const half8*)&hA[kt * 512];
#pragma unroll
      for (int s = 0; s < 4; ++s)
        acc[s] = __builtin_amdgcn_mfma_f32_16x16x32_f16(
            a, __builtin_bit_cast(half8, wg[s][kt]), acc[s], 0, 0, 0);
    }

    // wait ONLY for this step's 6 G loads (issued last iteration); never
    // drain the outp stores.
    if (staged) {
      if (outp) __builtin_amdgcn_s_waitcnt(WC_VM14);
      else      __builtin_amdgcn_s_waitcnt(WC_VM6);
    } else {
      __builtin_amdgcn_s_waitcnt(WC_VM0);
    }

    floatx4 gA[4];
#pragma unroll
    for (int c = 0; c < 4; ++c)
      gA[c] = *(const floatx4*)&Gs[buf][(w * 6 + c) * 256 + lane * 4];

#pragma unroll
    for (int s = 0; s < 2; ++s)
#pragma unroll
      for (int r = 0; r < 4; ++r) {
        float pre = acc[s][r] + gA[s][r];
        float g = __builtin_amdgcn_rcpf(1.f + __expf(-pre));
        rpk[wbase + s * 256 + r * 64] = (_Float16)(g * h_reg[s][r]);
      }
    float u_reg[2][4];
#pragma unroll
    for (int s = 0; s < 2; ++s)
#pragma unroll
      for (int r = 0; r < 4; ++r) {
        float pre = acc[2 + s][r] + gA[2 + s][r];
        u_reg[s][r] = __builtin_amdgcn_rcpf(1.f + __expf(-pre));
      }
    __builtin_amdgcn_s_waitcnt(WC_LGKM0);   // rpk visible
    __builtin_amdgcn_s_barrier();

    // ---------------- phase B: 2 candidate tiles --------------------------
    floatx4 accB[2] = {};
#pragma unroll
    for (int kt = 0; kt < 8; ++kt) {
      half8 a = *(const half8*)&rA[kt * 512];
#pragma unroll
      for (int s = 0; s < 2; ++s)
        accB[s] = __builtin_amdgcn_mfma_f32_16x16x32_f16(
            a, __builtin_bit_cast(half8, wc[s][kt]), accB[s], 0, 0, 0);
    }
    floatx4 gB[2];
#pragma unroll
    for (int s = 0; s < 2; ++s)
      gB[s] = *(const floatx4*)&Gs[buf][(w * 6 + 4 + s) * 256 + lane * 4];

#pragma unroll
    for (int s = 0; s < 2; ++s)
#pragma unroll
      for (int r = 0; r < 4; ++r) {
        int row = quad * 4 + r;
        float pre = accB[s][r] + gB[s][r];
        float c = 1.f - 2.f * __builtin_amdgcn_rcpf(1.f + __expf(2.f * pre));
        float u = u_reg[s][r];
        float hn = u * h_reg[s][r] + (1.f - u) * c;
        bool valid = (t0 + t) < seq4[r];
        hn = valid ? hn : h_reg[s][r];
        h_reg[s][r] = hn;
        hpk[wbase + s * 256 + r * 64] = (_Float16)hn;
        if (outp)
          outp[((size_t)(rg * RPB + row) * tc + t) * H_ + (w * 32 + s * 16 + l15)] =
              valid ? hn : 0.f;
      }
    __builtin_amdgcn_s_waitcnt(WC_LGKM0);   // hpk visible
    __builtin_amdgcn_s_barrier();
  }
  // --- save state from fp32 masters ---------------------------------------
#pragma unroll
  for (int s = 0; s < 2; ++s)
#pragma unroll
    for (int r = 0; r < 4; ++r)
      state[(size_t)(rg * RPB + quad * 4 + r) * H_ + (w * 32 + s * 16 + l15)] =
          h_reg[s][r];
}

// ---------------------------------------------------------------------------
// Final prediction: out[b, c] = [h_head | h_body] @ W_pred + b_pred.
// ---------------------------------------------------------------------------
__global__ __launch_bounds__(512) void pred_k(
    const float* __restrict__ hh, const float* __restrict__ hb,
    const float* __restrict__ Wp, const float* __restrict__ bpred,
    float* __restrict__ out)
{
  int tid = threadIdx.x;
  int b = tid >> 2, c = tid & 3;
  float acc = bpred[c];
  for (int k = 0; k < H_; ++k) acc += hh[b * H_ + k] * Wp[k * 4 + c];
  for (int k = 0; k < H_; ++k) acc += hb[b * H_ + k] * Wp[(H_ + k) * 4 + c];
  out[b * 4 + c] = acc;
}

// ---------------------------------------------------------------------------
extern "C" void kernel_launch(void* const* d_in, const int* in_sizes, int n_in,
                              void* d_out, int out_size, void* d_ws, size_t ws_size,
                              hipStream_t stream)
{
  (void)in_sizes; (void)n_in; (void)out_size;
  const int*   idsH = (const int*)  d_in[0];
  const int*   idsB = (const int*)  d_in[1];
  const float* emb  = (const float*)d_in[2];
  const float* Wp   = (const float*)d_in[3];
  const float* bp   = (const float*)d_in[4];
  const float* W[4][4];   // [hd0,hd1,bd0,bd1][Wg,bg,Wc,bc]
  for (int s = 0; s < 4; ++s)
    for (int q = 0; q < 4; ++q)
      W[s][q] = (const float*)d_in[5 + s * 4 + q];

  // choose time-chunk CH to fit ws_size (two G buffers for the pipeline)
  const size_t fixed_f = 1600000;
  int CH = 64;
  while (CH > 8 && (fixed_f + (size_t)BATCH * CH * (2 * NG + H_)) * 4 > ws_size)
    CH >>= 1;
  const int CHH = (CH < TH_) ? CH : TH_;

  float* wbase = (float*)d_ws;
  size_t off = 0;
  auto alloc = [&](size_t n) {
    float* p = wbase + off; off += (n + 255) & ~(size_t)255; return p;
  };
  int* seqH = (int*)alloc(BATCH);
  int* seqB = (int*)alloc(BATCH);
  float* Bx[4]; float* bi[4]; _Float16* Wpk[4];
  const int din[4] = {E_, H_, E_, H_};
  for (int s = 0; s < 4; ++s) {
    Bx[s]  = alloc((size_t)din[s] * NG);
    bi[s]  = alloc(NG);
    Wpk[s] = (_Float16*)alloc(48 * 8 * 64 * 8 / 2);   // 384 KB fp16
  }
  float* st0 = alloc((size_t)BATCH * H_);   // layer-0 carry (per stream, reused)
  float* hfH = alloc((size_t)BATCH * H_);   // head layer-1 carry/final
  float* hfB = alloc((size_t)BATCH * H_);   // body layer-1 carry/final
  float* Gc0 = alloc((size_t)BATCH * CH * NG);
  float* Gc1 = alloc((size_t)BATCH * CH * NG);
  float* Oc  = alloc((size_t)BATCH * CH * H_);
  (void)ws_size;

  // 1. pack weights
  for (int s = 0; s < 4; ++s) {
    int tot = din[s] * NG;
    pack_k<<<(tot + 255) / 256, 256, 0, stream>>>(
        W[s][0], W[s][1], W[s][2], W[s][3], din[s], Bx[s], bi[s]);
    pack_w<<<(48 * 64 + 255) / 256, 256, 0, stream>>>(
        W[s][0], W[s][2], din[s], Wpk[s]);
  }
  // 2. seqlens
  seq_k<<<BATCH, 256, 0, stream>>>(idsH, TH_, seqH);
  seq_k<<<BATCH, 256, 0, stream>>>(idsB, TB_, seqB);

  // 3. chunk-pipelined stream: fused dispatch runs L0(c) and L1(c-1)
  auto run_stream = [&](const int* ids, int T, int chs, const int* seq,
                        int l0, int l1, float* hf) {
    int nchunks = T / chs;
    int rows = BATCH * chs;
    dim3 g(rows / 64, NG / 64);
    for (int c = 0; c < nchunks; ++c) {
      int t0 = c * chs;
      gemm_in<<<g, 256, 0, stream>>>(nullptr, ids, emb, Bx[l0], bi[l0], Gc0,
                                     rows, E_, t0, chs, T);
      gru_pers<<<2 * NBLK, 512, 0, stream>>>(
          Gc0, Wpk[l0], seq, Oc, st0, t0, chs,
          (c > 0) ? Gc1 : nullptr, Wpk[l1], hf, (c - 1) * chs);
      gemm_in<<<g, 256, 0, stream>>>(Oc, nullptr, nullptr, Bx[l1], bi[l1], Gc1,
                                     rows, H_, 0, chs, T);
    }
    // drain: last layer-1 chunk
    gru_pers<<<2 * NBLK, 512, 0, stream>>>(
        nullptr, Wpk[l0], seq, nullptr, st0, 0, chs,
        Gc1, Wpk[l1], hf, (nchunks - 1) * chs);
  };
  run_stream(idsH, TH_, CHH, seqH, 0, 1, hfH);   // headline (hd0, hd1)
  run_stream(idsB, TB_, CH,  seqB, 2, 3, hfB);   // body     (bd0, bd1)

  // 4. prediction head
  pred_k<<<1, 512, 0, stream>>>(hfH, hfB, Wp, bp, (float*)d_out);
}

// Round 10
// 3312.740 us; speedup vs baseline: 2.0657x; 1.4034x over previous
//
#include <hip/hip_runtime.h>
#include <cstdint>
#include <cstddef>

// Problem constants: V=50000, E=300, NF=1, H=256, B=128, TH=32, TB=512, NC=4.
#define H_    256
#define NG    768      // 512 gate cols (r|u) + 256 candidate cols, packed
#define BATCH 128
#define TH_   32
#define TB_   512
#define E_    300
#define RPB   16             // batch rows per gru block
#define NBLK  (BATCH / RPB)  // 8 row-groups; fused grid = 16 blocks

typedef _Float16 half8 __attribute__((ext_vector_type(8)));
typedef float    floatx4 __attribute__((ext_vector_type(4)));

#define AS1 __attribute__((address_space(1)))
#define AS3 __attribute__((address_space(3)))

// s_waitcnt immediates (gfx9 encoding: vmcnt[3:0]=imm[3:0], vmcnt[5:4]=imm[15:14],
// expcnt=imm[6:4], lgkmcnt=imm[11:8]).
#define WC_LGKM0 0xC07F   // lgkmcnt(0), vmcnt/exp unconstrained
#define WC_VM14  0x0F7E   // vmcnt(14) only
#define WC_VM6   0x0F76   // vmcnt(6)  only
#define WC_VM0   0x0F70   // vmcnt(0)  only

// ---------------------------------------------------------------------------
// bias[j] = [bg | bc] (768)
// ---------------------------------------------------------------------------
__global__ __launch_bounds__(256) void pack_bias(
    const float* __restrict__ bg, const float* __restrict__ bc,
    float* __restrict__ bias)
{
  int idx = blockIdx.x * 256 + threadIdx.x;
  if (idx < NG) bias[idx] = (idx < 2 * H_) ? bg[idx] : bc[idx - 2 * H_];
}

// ---------------------------------------------------------------------------
// Pack INPUT-projection weights into fp16 MFMA B-frag tiles for gemm_mfma.
// Global layout [kt][nt][lane][8]: tile (nt 0..47, kt 0..KT-1) holds
// B[k = kt*32 + (l>>4)*8 + j][col = nt*16 + (l&15)], zero-padded k>=din.
// col<512 -> Wg, else Wc col-512.
// ---------------------------------------------------------------------------
__global__ __launch_bounds__(256) void pack_bx(
    const float* __restrict__ Wg, const float* __restrict__ Wc,
    int din, int KT, _Float16* __restrict__ out)
{
  int idx = blockIdx.x * 256 + threadIdx.x;
  if (idx >= KT * 48 * 64) return;
  int lane = idx & 63, tile = idx >> 6;
  int kt = tile / 48, nt = tile - kt * 48;
  int col = nt * 16 + (lane & 15);
  int k0 = kt * 32 + (lane >> 4) * 8;
  const float* W; int ncols, c2;
  if (col < 2 * H_) { W = Wg; ncols = 2 * H_; c2 = col; }
  else              { W = Wc; ncols = H_;     c2 = col - 2 * H_; }
  _Float16* dst = out + ((size_t)(kt * 48 + nt) * 64 + lane) * 8;
#pragma unroll
  for (int j = 0; j < 8; ++j) {
    int k = k0 + j;
    dst[j] = (k < din) ? (_Float16)W[(size_t)k * ncols + c2] : (_Float16)0.f;
  }
}

// ---------------------------------------------------------------------------
// Pack recurrent weights into fp16 MFMA B-fragment order (R7-validated).
// ---------------------------------------------------------------------------
__global__ __launch_bounds__(256) void pack_w(
    const float* __restrict__ Wg, const float* __restrict__ Wc, int din,
    _Float16* __restrict__ wpk)
{
  int idx = blockIdx.x * 256 + threadIdx.x;
  if (idx >= 48 * 64) return;
  int tile = idx >> 6, lane = idx & 63;
  int grp = tile >> 4, tt = tile & 15;
  int wv = tt >> 1, s = tt & 1;
  const float* W; int ncols, n0;
  if (grp == 0)      { W = Wg; ncols = 2 * H_; n0 = wv * 32 + s * 16; }
  else if (grp == 1) { W = Wg; ncols = 2 * H_; n0 = 256 + wv * 32 + s * 16; }
  else               { W = Wc; ncols = H_;     n0 = wv * 32 + s * 16; }
  int n = n0 + (lane & 15);
  int kb = (lane >> 4) * 8;
#pragma unroll
  for (int kt = 0; kt < 8; ++kt) {
    _Float16* dst = wpk + ((size_t)(tile * 8 + kt) * 64 + lane) * 8;
#pragma unroll
    for (int j = 0; j < 8; ++j)
      dst[j] = (_Float16)W[(size_t)(din + kt * 32 + kb + j) * ncols + n];
  }
}

// ---------------------------------------------------------------------------
// seqlen[b] = #nonzero ids in row b (valid steps form a prefix).
// ---------------------------------------------------------------------------
__global__ __launch_bounds__(256) void seq_k(const int* __restrict__ ids, int T,
                                             int* __restrict__ seq)
{
  __shared__ int red[256];
  int b = blockIdx.x, tid = threadIdx.x;
  int cnt = 0;
  for (int t = tid; t < T; t += 256) cnt += (ids[b * T + t] != 0) ? 1 : 0;
  red[tid] = cnt;
  __syncthreads();
  for (int s = 128; s > 0; s >>= 1) {
    if (tid < s) red[tid] += red[tid + s];
    __syncthreads();
  }
  if (tid == 0) seq[b] = red[0];
}

// ---------------------------------------------------------------------------
// MFMA input-projection GEMM (R10, replaces fp32 gemm_in).
// Block 256 thr (4 waves), tile M=64 x N=128, K in 32-ktiles (KT of them).
// A fp32 source (emb gather or Adir) converted to fp16 in LDS (row stride
// 40 halves -> A b128 reads 2-way = free); B staged from pre-packed frag
// tiles via global_load_lds. Wave w owns col strip [w*32, w*32+32).
// Output: fragment-packed G (R9-validated layout, consumed by gru_pers):
//   G[(tl*BATCH + rg*16)*768 + ((ww*6 + 2g+s)*64 + qb*16 + ll)*4 + rb]
// ---------------------------------------------------------------------------
__global__ __launch_bounds__(256) void gemm_mfma(
    const float* __restrict__ Adir, const int* __restrict__ ids,
    const float* __restrict__ emb,
    const _Float16* __restrict__ Bpk, const float* __restrict__ bias,
    float* __restrict__ G, int K, int KT, int t0, int tcsh, int T)
{
  __shared__ __align__(16) _Float16 Al[2][64 * 40];
  __shared__ __align__(16) _Float16 Bl[2][8 * 512];
  const int tid = threadIdx.x;
  const int w = tid >> 6, lane = tid & 63;
  const int quad = lane >> 4, l15 = lane & 15;
  const int m0 = blockIdx.x * 64;
  const int n0 = blockIdx.y * 128;
  const int tc = 1 << tcsh;

  // A-load mapping: row am = tid>>2 (0..63), k-quarter akq = tid&3
  const int am = tid >> 2, akq = tid & 3;
  const int arow = m0 + am;
  const float* asrc;
  if (Adir) {
    asrc = Adir + (size_t)arow * K;
  } else {
    int b = arow >> tcsh, tl = arow & (tc - 1);
    asrc = emb + (size_t)ids[b * T + t0 + tl] * K;
  }

  float a8[8];
  auto loadA = [&](int kt) {
    int k0 = kt * 32 + akq * 8;
#pragma unroll
    for (int j = 0; j < 8; ++j) a8[j] = (k0 + j < K) ? asrc[k0 + j] : 0.f;
  };
  auto writeA = [&](int buf) {
    half8 v;
#pragma unroll
    for (int j = 0; j < 8; ++j) v[j] = (_Float16)a8[j];
    *(half8*)&Al[buf][am * 40 + akq * 8] = v;
  };
  auto stageB = [&](int kt, int buf) {
#pragma unroll
    for (int i = 0; i < 2; ++i) {
      int nt = (n0 >> 4) + w * 2 + i;
      const _Float16* src = Bpk + ((size_t)(kt * 48 + nt) * 64 + lane) * 8;
      __builtin_amdgcn_global_load_lds(
          (const AS1 unsigned int*)src,
          (AS3 unsigned int*)&Bl[buf][(w * 2 + i) * 512 + lane * 8], 16, 0, 0);
    }
  };

  loadA(0);
  stageB(0, 0);
  writeA(0);
  floatx4 acc[4][2] = {};

  for (int kt = 0; kt < KT; ++kt) {
    const int buf = kt & 1;
    __syncthreads();                       // buf fully staged for all waves
    if (kt + 1 < KT) { loadA(kt + 1); stageB(kt + 1, buf ^ 1); }
    half8 bf0 = *(const half8*)&Bl[buf][(w * 2 + 0) * 512 + lane * 8];
    half8 bf1 = *(const half8*)&Bl[buf][(w * 2 + 1) * 512 + lane * 8];
#pragma unroll
    for (int st = 0; st < 4; ++st) {
      half8 af = *(const half8*)&Al[buf][(st * 16 + l15) * 40 + quad * 8];
      acc[st][0] = __builtin_amdgcn_mfma_f32_16x16x32_f16(af, bf0, acc[st][0], 0, 0, 0);
      acc[st][1] = __builtin_amdgcn_mfma_f32_16x16x32_f16(af, bf1, acc[st][1], 0, 0, 0);
    }
    if (kt + 1 < KT) writeA(buf ^ 1);      // buf^1 free: all reads done pre-sync
  }

  // epilogue: bias + fragment-packed G stores
  float bb[2] = { bias[n0 + w * 32 + l15], bias[n0 + w * 32 + 16 + l15] };
#pragma unroll
  for (int s = 0; s < 2; ++s) {
    int col = n0 + w * 32 + s * 16 + l15;
    int g = col >> 8, kk = col & 255;
    int ww = kk >> 5, ss = (kk >> 4) & 1, ll = kk & 15;
    int cc = 2 * g + ss;
#pragma unroll
    for (int st = 0; st < 4; ++st) {
#pragma unroll
      for (int r = 0; r < 4; ++r) {
        int grow = m0 + st * 16 + quad * 4 + r;
        int b = grow >> tcsh, tl = grow & (tc - 1);
        int rg = b >> 4, mm = b & 15, qb = mm >> 2, rb = mm & 3;
        G[((size_t)tl * BATCH + rg * RPB) * NG +
          ((ww * 6 + cc) * 64 + qb * 16 + ll) * 4 + rb] = acc[st][s][r] + bb[s];
      }
    }
  }
}

// ---------------------------------------------------------------------------
// Persistent-weight fused GRU (R9, unchanged). 16 blocks x 512 thr, 1/CU.
// ---------------------------------------------------------------------------
__global__ __launch_bounds__(512, 1) void gru_pers(
    const float* __restrict__ G0, const _Float16* __restrict__ W0,
    const int* __restrict__ seq, float* __restrict__ out0,
    float* __restrict__ st0, int t00, int tc,
    const float* __restrict__ G1, const _Float16* __restrict__ W1,
    float* __restrict__ st1, int t01)
{
  __shared__ __align__(16) _Float16 hpk[4096];    // h frags (fp16)
  __shared__ __align__(16) _Float16 rpk[4096];    // r*h frags (fp16)
  __shared__ __align__(16) float Gs[2][12288];    // staged G, wave-private

  const int bid = blockIdx.x;
  const float* G; const _Float16* Wsrc; float* outp; float* state; int t0, rg;
  if (bid < NBLK) { G = G0; Wsrc = W0; outp = out0; state = st0; t0 = t00; rg = bid; }
  else            { G = G1; Wsrc = W1; outp = nullptr; state = st1; t0 = t01; rg = bid - NBLK; }
  if (!G) return;

  const int tid = threadIdx.x;
  const int w = tid >> 6, lane = tid & 63;
  const int quad = lane >> 4, l15 = lane & 15;

  // --- load weights once; pin (blocks rematerialization/sinking) ----------
  floatx4 wg[4][8];   // gate tiles -> VGPRs
  floatx4 wc[2][8];   // candidate tiles -> AGPRs
#pragma unroll
  for (int i = 0; i < 4; ++i) {
    const int tile = (i >> 1) * 16 + w * 2 + (i & 1);
#pragma unroll
    for (int kt = 0; kt < 8; ++kt) {
      wg[i][kt] = *(const floatx4*)&Wsrc[((size_t)(tile * 8 + kt) * 64 + lane) * 8];
      asm volatile("" : "+v"(wg[i][kt]));
    }
  }
#pragma unroll
  for (int i = 0; i < 2; ++i) {
    const int tile = 32 + w * 2 + i;
#pragma unroll
    for (int kt = 0; kt < 8; ++kt) {
      wc[i][kt] = *(const floatx4*)&Wsrc[((size_t)(tile * 8 + kt) * 64 + lane) * 8];
      asm volatile("" : "+a"(wc[i][kt]));
    }
  }

  // --- seq / steps ---------------------------------------------------------
  int seq4[4];
#pragma unroll
  for (int r = 0; r < 4; ++r) seq4[r] = seq[rg * RPB + quad * 4 + r];
  int Smax = 0;
#pragma unroll
  for (int i = 0; i < 16; ++i) Smax = max(Smax, seq[rg * RPB + i]);
  int steps = Smax - t0;
  if (steps < 0) steps = 0;
  if (steps > tc) steps = tc;

  // --- frag addressing (R7-validated bank-exact layout) --------------------
  const int wbase = (w * 64 + quad * 2 + (l15 >> 3)) * 8 + (l15 & 7);
  const int rbase = (((quad >> 1) << 5) + ((l15 & 3) << 3) +
                     ((l15 >> 2) << 1) + (quad & 1)) * 8;

  // --- h_reg init + h frag fill -------------------------------------------
  float h_reg[2][4];
#pragma unroll
  for (int s = 0; s < 2; ++s)
#pragma unroll
    for (int r = 0; r < 4; ++r) {
      int row = quad * 4 + r, k = w * 32 + s * 16 + l15;
      float v = (t0 == 0) ? 0.f : state[(size_t)(rg * RPB + row) * H_ + k];
      h_reg[s][r] = v;
      hpk[wbase + s * 256 + r * 64] = (_Float16)v;
    }

  // --- async G staging: wave w copies its own 6 chunks (1 KB each) --------
  const float* gblk = G + (size_t)rg * RPB * NG + w * (6 * 256);
  float* ldsw = &Gs[0][0] + w * (6 * 256);
  auto stage = [&](int t, int buf) {
    const float* gp = gblk + (size_t)t * BATCH * NG;
    float* lp = ldsw + buf * 12288;
#pragma unroll
    for (int c = 0; c < 6; ++c) {
      __builtin_amdgcn_global_load_lds(
          (const AS1 unsigned int*)(gp + c * 256 + lane * 4),
          (AS3 unsigned int*)(lp + c * 256), 16, 0, 0);
    }
  };
  if (steps > 0) stage(0, 0);
  __syncthreads();   // one full drain: loads for t=0 complete + hpk visible

  const _Float16* hA = &hpk[rbase];
  const _Float16* rA = &rpk[rbase];

  for (int t = 0; t < steps; ++t) {
    const int buf = t & 1;
    const bool staged = (t + 1 < steps);
    if (staged) stage(t + 1, buf ^ 1);   // async prefetch next step's G

    // ---------------- phase A: 4 gate tiles (r s=0,1 ; u s=0,1) ----------
    floatx4 acc[4] = {};
#pragma unroll
    for (int kt = 0; kt < 8; ++kt) {
      half8 a = *(const half8*)&hA[kt * 512];
#pragma unroll
      for (int s = 0; s < 4; ++s)
        acc[s] = __builtin_amdgcn_mfma_f32_16x16x32_f16(
            a, __builtin_bit_cast(half8, wg[s][kt]), acc[s], 0, 0, 0);
    }

    if (staged) {
      if (outp) __builtin_amdgcn_s_waitcnt(WC_VM14);
      else      __builtin_amdgcn_s_waitcnt(WC_VM6);
    } else {
      __builtin_amdgcn_s_waitcnt(WC_VM0);
    }

    floatx4 gA[4];
#pragma unroll
    for (int c = 0; c < 4; ++c)
      gA[c] = *(const floatx4*)&Gs[buf][(w * 6 + c) * 256 + lane * 4];

#pragma unroll
    for (int s = 0; s < 2; ++s)
#pragma unroll
      for (int r = 0; r < 4; ++r) {
        float pre = acc[s][r] + gA[s][r];
        float g = __builtin_amdgcn_rcpf(1.f + __expf(-pre));
        rpk[wbase + s * 256 + r * 64] = (_Float16)(g * h_reg[s][r]);
      }
    float u_reg[2][4];
#pragma unroll
    for (int s = 0; s < 2; ++s)
#pragma unroll
      for (int r = 0; r < 4; ++r) {
        float pre = acc[2 + s][r] + gA[2 + s][r];
        u_reg[s][r] = __builtin_amdgcn_rcpf(1.f + __expf(-pre));
      }
    __builtin_amdgcn_s_waitcnt(WC_LGKM0);   // rpk visible
    __builtin_amdgcn_s_barrier();

    // ---------------- phase B: 2 candidate tiles --------------------------
    floatx4 accB[2] = {};
#pragma unroll
    for (int kt = 0; kt < 8; ++kt) {
      half8 a = *(const half8*)&rA[kt * 512];
#pragma unroll
      for (int s = 0; s < 2; ++s)
        accB[s] = __builtin_amdgcn_mfma_f32_16x16x32_f16(
            a, __builtin_bit_cast(half8, wc[s][kt]), accB[s], 0, 0, 0);
    }
    floatx4 gB[2];
#pragma unroll
    for (int s = 0; s < 2; ++s)
      gB[s] = *(const floatx4*)&Gs[buf][(w * 6 + 4 + s) * 256 + lane * 4];

#pragma unroll
    for (int s = 0; s < 2; ++s)
#pragma unroll
      for (int r = 0; r < 4; ++r) {
        int row = quad * 4 + r;
        float pre = accB[s][r] + gB[s][r];
        float c = 1.f - 2.f * __builtin_amdgcn_rcpf(1.f + __expf(2.f * pre));
        float u = u_reg[s][r];
        float hn = u * h_reg[s][r] + (1.f - u) * c;
        bool valid = (t0 + t) < seq4[r];
        hn = valid ? hn : h_reg[s][r];
        h_reg[s][r] = hn;
        hpk[wbase + s * 256 + r * 64] = (_Float16)hn;
        if (outp)
          outp[((size_t)(rg * RPB + row) * tc + t) * H_ + (w * 32 + s * 16 + l15)] =
              valid ? hn : 0.f;
      }
    __builtin_amdgcn_s_waitcnt(WC_LGKM0);   // hpk visible
    __builtin_amdgcn_s_barrier();
  }
  // --- save state from fp32 masters ---------------------------------------
#pragma unroll
  for (int s = 0; s < 2; ++s)
#pragma unroll
    for (int r = 0; r < 4; ++r)
      state[(size_t)(rg * RPB + quad * 4 + r) * H_ + (w * 32 + s * 16 + l15)] =
          h_reg[s][r];
}

// ---------------------------------------------------------------------------
// Final prediction: out[b, c] = [h_head | h_body] @ W_pred + b_pred.
// ---------------------------------------------------------------------------
__global__ __launch_bounds__(512) void pred_k(
    const float* __restrict__ hh, const float* __restrict__ hb,
    const float* __restrict__ Wp, const float* __restrict__ bpred,
    float* __restrict__ out)
{
  int tid = threadIdx.x;
  int b = tid >> 2, c = tid & 3;
  float acc = bpred[c];
  for (int k = 0; k < H_; ++k) acc += hh[b * H_ + k] * Wp[k * 4 + c];
  for (int k = 0; k < H_; ++k) acc += hb[b * H_ + k] * Wp[(H_ + k) * 4 + c];
  out[b * 4 + c] = acc;
}

// ---------------------------------------------------------------------------
extern "C" void kernel_launch(void* const* d_in, const int* in_sizes, int n_in,
                              void* d_out, int out_size, void* d_ws, size_t ws_size,
                              hipStream_t stream)
{
  (void)in_sizes; (void)n_in; (void)out_size;
  const int*   idsH = (const int*)  d_in[0];
  const int*   idsB = (const int*)  d_in[1];
  const float* emb  = (const float*)d_in[2];
  const float* Wp   = (const float*)d_in[3];
  const float* bp   = (const float*)d_in[4];
  const float* W[4][4];   // [hd0,hd1,bd0,bd1][Wg,bg,Wc,bc]
  for (int s = 0; s < 4; ++s)
    for (int q = 0; q < 4; ++q)
      W[s][q] = (const float*)d_in[5 + s * 4 + q];

  // choose time-chunk CH to fit ws_size (two G buffers for the pipeline)
  const size_t fixed_f = 1600000;
  int CH = 64;
  while (CH > 8 && (fixed_f + (size_t)BATCH * CH * (2 * NG + H_)) * 4 > ws_size)
    CH >>= 1;
  const int CHH = (CH < TH_) ? CH : TH_;
  const int tcshB = __builtin_ctz(CH), tcshH = __builtin_ctz(CHH);

  float* wbase = (float*)d_ws;
  size_t off = 0;
  auto alloc = [&](size_t n) {
    float* p = wbase + off; off += (n + 255) & ~(size_t)255; return p;
  };
  int* seqH = (int*)alloc(BATCH);
  int* seqB = (int*)alloc(BATCH);
  float* bi[4]; _Float16* Wpk[4]; _Float16* Bxh[4];
  const int din[4] = {E_, H_, E_, H_};
  const int KT[4]  = {10, 8, 10, 8};        // ceil(din/32)
  for (int s = 0; s < 4; ++s) {
    bi[s]  = alloc(NG);
    Wpk[s] = (_Float16*)alloc(48 * 8 * 64 * 8 / 2);       // 384 KB fp16
    Bxh[s] = (_Float16*)alloc((size_t)10 * 48 * 64 * 8 / 2); // ≤480 KB fp16
  }
  float* st0 = alloc((size_t)BATCH * H_);   // layer-0 carry (per stream, reused)
  float* hfH = alloc((size_t)BATCH * H_);   // head layer-1 carry/final
  float* hfB = alloc((size_t)BATCH * H_);   // body layer-1 carry/final
  float* Gc0 = alloc((size_t)BATCH * CH * NG);
  float* Gc1 = alloc((size_t)BATCH * CH * NG);
  float* Oc  = alloc((size_t)BATCH * CH * H_);
  (void)ws_size;

  // 1. pack weights
  for (int s = 0; s < 4; ++s) {
    pack_bias<<<(NG + 255) / 256, 256, 0, stream>>>(W[s][1], W[s][3], bi[s]);
    pack_w<<<(48 * 64 + 255) / 256, 256, 0, stream>>>(
        W[s][0], W[s][2], din[s], Wpk[s]);
    pack_bx<<<(KT[s] * 48 * 64 + 255) / 256, 256, 0, stream>>>(
        W[s][0], W[s][2], din[s], KT[s], Bxh[s]);
  }
  // 2. seqlens
  seq_k<<<BATCH, 256, 0, stream>>>(idsH, TH_, seqH);
  seq_k<<<BATCH, 256, 0, stream>>>(idsB, TB_, seqB);

  // 3. chunk-pipelined stream: fused gru dispatch runs L0(c) and L1(c-1)
  auto run_stream = [&](const int* ids, int T, int chs, int tcsh,
                        const int* seq, int l0, int l1, float* hf) {
    int nchunks = T / chs;
    int rows = BATCH * chs;
    dim3 gg(rows / 64, NG / 128);
    for (int c = 0; c < nchunks; ++c) {
      int t0 = c * chs;
      gemm_mfma<<<gg, 256, 0, stream>>>(nullptr, ids, emb, Bxh[l0], bi[l0],
                                        Gc0, E_, KT[l0], t0, tcsh, T);
      gru_pers<<<2 * NBLK, 512, 0, stream>>>(
          Gc0, Wpk[l0], seq, Oc, st0, t0, chs,
          (c > 0) ? Gc1 : nullptr, Wpk[l1], hf, (c - 1) * chs);
      gemm_mfma<<<gg, 256, 0, stream>>>(Oc, nullptr, nullptr, Bxh[l1], bi[l1],
                                        Gc1, H_, KT[l1], 0, tcsh, T);
    }
    // drain: last layer-1 chunk
    gru_pers<<<2 * NBLK, 512, 0, stream>>>(
        nullptr, Wpk[l0], seq, nullptr, st0, 0, chs,
        Gc1, Wpk[l1], hf, (nchunks - 1) * chs);
  };
  run_stream(idsH, TH_, CHH, tcshH, seqH, 0, 1, hfH);   // headline (hd0, hd1)
  run_stream(idsB, TB_, CH,  tcshB, seqB, 2, 3, hfB);   // body     (bd0, bd1)

  // 4. prediction head
  pred_k<<<1, 512, 0, stream>>>(hfH, hfB, Wp, bp, (float*)d_out);
}